// Round 2
// baseline (9882.327 us; speedup 1.0000x reference)
//
#include <hip/hip_runtime.h>
#include <cstdint>
#include <cstddef>

#define BB 128   // batch
#define EE 512   // input dim
#define HH 1024  // hidden
#define G4 4096
#define OO 512   // output dim
#define NBLKP 128    // persistent grid: 128 blocks on 256 CUs -> 2x residency headroom
#define NTHR 1024    // 16 waves
#define RED36 36     // reduce-buffer row stride (floats): <=2-way bank conflicts
#define SMEM_BYTES (131072 + BB * RED36 * 4)  // W hi+lo (2x64KB) + red
#define SPIN_LIMIT (1u << 20)  // ~30ms bail: deadlock -> wrong answer, not dead container

typedef float f32x4 __attribute__((ext_vector_type(4)));
typedef short s16x8 __attribute__((ext_vector_type(8)));
typedef __bf16 b16x8 __attribute__((ext_vector_type(8)));

// ---- mfma dispatch: tolerate either short8- or bf16x8-typed builtin ----
template <typename V>
__device__ __forceinline__ auto mfma_try(V a, V b, f32x4 c, int)
    -> decltype(__builtin_amdgcn_mfma_f32_16x16x32_bf16(a, b, c, 0, 0, 0)) {
  return __builtin_amdgcn_mfma_f32_16x16x32_bf16(a, b, c, 0, 0, 0);
}
template <typename V>
__device__ __forceinline__ f32x4 mfma_try(V a, V b, f32x4 c, long) {
  b16x8 ab = __builtin_bit_cast(b16x8, a);
  b16x8 bb = __builtin_bit_cast(b16x8, b);
  return __builtin_amdgcn_mfma_f32_16x16x32_bf16(ab, bb, c, 0, 0, 0);
}
__device__ __forceinline__ f32x4 mfma_bf16(s16x8 a, s16x8 b, f32x4 c) {
  return mfma_try(a, b, c, 0);
}

__device__ __forceinline__ float bf2f(ushort s) {
  unsigned int u = ((unsigned int)s) << 16;
  return __builtin_bit_cast(float, u);
}
__device__ __forceinline__ ushort f2bf(float f) {
  unsigned int u = __builtin_bit_cast(unsigned int, f);
  unsigned int r = (u + 0x7fffu + ((u >> 16) & 1u)) >> 16;
  return (ushort)r;
}
__device__ __forceinline__ float sigm(float x) {
  return 1.0f / (1.0f + __expf(-x));
}

// ======== fp32 -> split bf16 (hi+lo) for x, W_ih, W_hh, fc_w ============
__global__ void __launch_bounds__(256)
convert_split(const float* __restrict__ x, const float* __restrict__ Wih,
              const float* __restrict__ Whh, const float* __restrict__ fcw,
              ushort* __restrict__ xh, ushort* __restrict__ xl,
              ushort* __restrict__ Wihh, ushort* __restrict__ Wihl,
              ushort* __restrict__ Whhh, ushort* __restrict__ Whhl,
              ushort* __restrict__ fcwh, ushort* __restrict__ fcwl,
              unsigned* __restrict__ bar) {
  if (blockIdx.x == 0 && threadIdx.x == 0) { bar[0] = 0u; bar[1] = 0u; }
  const long n0 = (long)BB * EE;
  const long n1 = n0 + (long)G4 * EE;
  const long n2 = n1 + (long)G4 * HH;
  long i = ((long)blockIdx.x * 256 + threadIdx.x) * 4;
  const float* src;
  ushort *dh, *dl;
  long off;
  if (i < n0) {
    src = x; dh = xh; dl = xl; off = i;
  } else if (i < n1) {
    src = Wih; dh = Wihh; dl = Wihl; off = i - n0;
  } else if (i < n2) {
    src = Whh; dh = Whhh; dl = Whhl; off = i - n1;
  } else {
    src = fcw; dh = fcwh; dl = fcwl; off = i - n2;
  }
  float4 v = *(const float4*)&src[off];
  ushort4 h;
  h.x = f2bf(v.x); h.y = f2bf(v.y); h.z = f2bf(v.z); h.w = f2bf(v.w);
  *(ushort4*)&dh[off] = h;
  ushort4 l;
  l.x = f2bf(v.x - bf2f(h.x));
  l.y = f2bf(v.y - bf2f(h.y));
  l.z = f2bf(v.z - bf2f(h.z));
  l.w = f2bf(v.w - bf2f(h.w));
  *(ushort4*)&dl[off] = l;
}

// ========== z = x @ W_ih^T + (b_ih+b_hh) -> zbuf fp32 [B][4H] ===========
__global__ void __launch_bounds__(256)
z_split(const ushort* __restrict__ xh, const ushort* __restrict__ xl,
        const ushort* __restrict__ Wihh, const ushort* __restrict__ Wihl,
        const float* __restrict__ bih, const float* __restrict__ bhh,
        float* __restrict__ zbuf) {
  __shared__ alignas(16) ushort Ah[64][72];
  __shared__ alignas(16) ushort Al[64][72];
  __shared__ alignas(16) ushort Bh[32][72];
  __shared__ alignas(16) ushort Bl[32][72];
  const int tid = threadIdx.x, bid = blockIdx.x;
  const int m0 = (bid >> 7) * 64;
  const int hbase = (bid & 127) * 8;
  const int lane = tid & 63, wave = tid >> 6;
  const int wm = wave & 1, wn = wave >> 1;
  const int fr_row = lane & 15, fr_k = (lane >> 4) * 8;
  const f32x4 fz = {0.f, 0.f, 0.f, 0.f};

  f32x4 a0 = fz, a1 = fz;
  for (int kt = 0; kt < EE / 64; ++kt) {
    for (int i = 0; i < 2; ++i) {
      int idx = tid + i * 256;
      int r = idx >> 3, c8 = (idx & 7) * 8;
      int go = (m0 + r) * EE + kt * 64 + c8;
      *(uint4*)&Ah[r][c8] = *(const uint4*)&xh[go];
      *(uint4*)&Al[r][c8] = *(const uint4*)&xl[go];
    }
    {
      int r = tid >> 3, c8 = (tid & 7) * 8;
      int wrow = (r >> 3) * HH + hbase + (r & 7);
      int go = wrow * EE + kt * 64 + c8;
      *(uint4*)&Bh[r][c8] = *(const uint4*)&Wihh[go];
      *(uint4*)&Bl[r][c8] = *(const uint4*)&Wihl[go];
    }
    __syncthreads();
    for (int kc = 0; kc < 2; ++kc) {
      int ko = kc * 32 + fr_k;
      s16x8 bh = *(const s16x8*)&Bh[wn * 16 + fr_row][ko];
      s16x8 bl = *(const s16x8*)&Bl[wn * 16 + fr_row][ko];
      s16x8 f0h = *(const s16x8*)&Ah[wm * 32 + fr_row][ko];
      s16x8 f0l = *(const s16x8*)&Al[wm * 32 + fr_row][ko];
      s16x8 f1h = *(const s16x8*)&Ah[wm * 32 + 16 + fr_row][ko];
      s16x8 f1l = *(const s16x8*)&Al[wm * 32 + 16 + fr_row][ko];
      a0 = mfma_bf16(f0h, bh, a0);
      a0 = mfma_bf16(f0l, bh, a0);
      a0 = mfma_bf16(f0h, bl, a0);
      a1 = mfma_bf16(f1h, bh, a1);
      a1 = mfma_bf16(f1l, bh, a1);
      a1 = mfma_bf16(f1h, bl, a1);
    }
    __syncthreads();
  }
  int jcol = wn * 16 + fr_row;
  int gc = (jcol >> 3) * HH + hbase + (jcol & 7);
  float bias = bih[gc] + bhh[gc];
  int rbase = wm * 32 + (lane >> 4) * 4;
#pragma unroll
  for (int r = 0; r < 4; ++r) {
    zbuf[(size_t)(m0 + rbase + r) * G4 + gc] = a0[r] + bias;
    zbuf[(size_t)(m0 + rbase + 16 + r) * G4 + gc] = a1[r] + bias;
  }
}

// =====================================================================
// Persistent kernel (PLAIN launch — capture-safe): all T steps.
//   128 blocks x 1024 thr: each block = all 128 batch rows x 8 h-cols.
//   Its 32 W_hh gate rows (hi+lo, 128 KB) stay in LDS whole kernel,
//   XOR-swizzled (byte ^= (row&7)<<4) -> ds_read_b128 conflict-free.
//   z, c-state, fc_w frags in registers. Hand-rolled agent-scope grid
//   barrier per step (release wbl2 / acquire inv); FC for h_{t-1} runs
//   in the arrive->wait slack (h 4-deep buffered; max skew is 2 slots).
//   Spin bails after SPIN_LIMIT -> worst case wrong answer, never hang.
// =====================================================================
__global__ void __launch_bounds__(NTHR)
persist_kernel(const ushort* __restrict__ Whhh, const ushort* __restrict__ Whhl,
               const float* __restrict__ zbuf,
               ushort* __restrict__ hbh, ushort* __restrict__ hbl,
               const ushort* __restrict__ fcwh, const ushort* __restrict__ fcwl,
               const float* __restrict__ fcb, float* __restrict__ out,
               float* __restrict__ out_ns, unsigned* __restrict__ bar, int T) {
  extern __shared__ char smem[];
  char* WlB = smem + 65536;               // lo plane
  float* red = (float*)(smem + 131072);   // [128][RED36] f32

  const int tid = threadIdx.x;
  const int hb = blockIdx.x;      // h-slice (8 cols)
  const int lane = tid & 63;
  const int w = tid >> 6;         // 0..15
  const int wm = w & 7;           // m-tile (16 rows) -> 8x16 = 128 rows
  const int wk = w >> 3;          // K half (512)
  const int fr = lane & 15;
  const int fk8 = (lane >> 4) * 8;
  const int swz = (fr & 7) << 4;
  const f32x4 fz = {0.f, 0.f, 0.f, 0.f};

  // ---- stage W_hh tile into LDS once (swizzled) ----
  for (int i = tid; i < 32 * 128; i += NTHR) {
    int r = i >> 7;                 // local gate row (= g*8+c)
    int cb = (i & 127) * 16;        // byte within row
    int g = r >> 3, c = r & 7;
    size_t go = ((size_t)(g * HH + hb * 8 + c)) * (HH * 2) + (size_t)cb;
    int lofs = r * 2048 + (cb ^ ((r & 7) << 4));
    *(uint4*)(smem + lofs) = *(const uint4*)((const char*)Whhh + go);
    *(uint4*)(WlB + lofs) = *(const uint4*)((const char*)Whhl + go);
  }

  // ---- per-thread cell state + z preload (all 1024 threads own a cell) ----
  const int crow = tid >> 3, ccol = tid & 7;
  float creg = 0.f;
  size_t zb = (size_t)crow * G4 + hb * 8 + ccol;
  float zi = zbuf[zb];
  float zf = zbuf[zb + HH];
  float zg = zbuf[zb + 2 * HH];
  float zo = zbuf[zb + 3 * HH];

  // ---- FC constants: block = 16 out-rows x 32 out-cols; 16 waves =
  //      2 col-halves x 8-way K-split(128). fc_w frags in registers. ----
  const int m0f = (hb >> 4) * 16;
  const int o0 = (hb & 15) * 32;
  const int wo = w & 1, wkf = w >> 1;
  s16x8 fbh[4], fbl[4];
  {
    size_t base = (size_t)(o0 + wo * 16 + fr) * HH + wkf * 128 + fk8;
#pragma unroll
    for (int j = 0; j < 4; ++j) {
      fbh[j] = *(const s16x8*)&fcwh[base + j * 32];
      fbl[j] = *(const s16x8*)&fcwl[base + j * 32];
    }
  }
  float fcbv = 0.f;
  if (tid < 512) fcbv = fcb[o0 + (tid >> 8) * 16 + (tid & 15)];
  __syncthreads();  // W staged

  for (int t = 0; t <= T; ++t) {
    if (t < T) {
      if (t > 0) {
        // ---- gates: h_{t-1} @ Whh^T (K split 2-way across waves) ----
        const ushort* hph = hbh + (size_t)((t - 1) & 3) * (BB * HH);
        const ushort* hpl = hbl + (size_t)((t - 1) & 3) * (BB * HH);
        const int arow = wm * 16 + fr;
        const ushort* ha = hph + (size_t)arow * HH + wk * 512;
        const ushort* la = hpl + (size_t)arow * HH + wk * 512;
        f32x4 a0 = fz, a1 = fz;
        for (int kt = 0; kt < 16; ++kt) {
          int kk = kt * 32 + fk8;
          s16x8 ah = *(const s16x8*)&ha[kk];
          s16x8 al = *(const s16x8*)&la[kk];
          int sw = ((wk * 512 + kk) * 2) ^ swz;
          int ofs0 = fr * 2048 + sw;
          int ofs1 = (16 + fr) * 2048 + sw;
          s16x8 bh0 = *(const s16x8*)(smem + ofs0);
          s16x8 bl0 = *(const s16x8*)(WlB + ofs0);
          s16x8 bh1 = *(const s16x8*)(smem + ofs1);
          s16x8 bl1 = *(const s16x8*)(WlB + ofs1);
          a0 = mfma_bf16(ah, bh0, a0);
          a0 = mfma_bf16(al, bh0, a0);
          a0 = mfma_bf16(ah, bl0, a0);
          a1 = mfma_bf16(ah, bh1, a1);
          a1 = mfma_bf16(al, bh1, a1);
          a1 = mfma_bf16(ah, bl1, a1);
        }
        // ---- reduce 2 K-halves in LDS ----
        int rrow = wm * 16 + (lane >> 4) * 4;
        if (wk == 1) {
#pragma unroll
          for (int r = 0; r < 4; ++r) {
            red[(rrow + r) * RED36 + fr] = a0[r];
            red[(rrow + r) * RED36 + 16 + fr] = a1[r];
          }
        }
        __syncthreads();
        if (wk == 0) {
#pragma unroll
          for (int r = 0; r < 4; ++r) {
            red[(rrow + r) * RED36 + fr] += a0[r];
            red[(rrow + r) * RED36 + 16 + fr] += a1[r];
          }
        }
        __syncthreads();
      }
      // ---- LSTM cell (fp32, c in register), write split-bf16 h_t ----
      {
        float gi = zi, gf = zf, gg = zg, go_ = zo;
        if (t > 0) {
          const float* rp = red + crow * RED36;
          gi += rp[ccol];
          gf += rp[8 + ccol];
          gg += rp[16 + ccol];
          go_ += rp[24 + ccol];
        }
        float iv = sigm(gi), fv = sigm(gf), gv = tanhf(gg), ov = sigm(go_);
        creg = fv * creg + iv * gv;
        float hv = ov * tanhf(creg);
        ushort hh = f2bf(hv);
        ushort hl = f2bf(hv - bf2f(hh));
        size_t ho = (size_t)(t & 3) * (BB * HH) + (size_t)crow * HH + hb * 8 + ccol;
        hbh[ho] = hh;
        hbl[ho] = hl;
        if (t == T - 1 && crow == BB - 1) out_ns[hb * 8 + ccol] = hv;
      }
      // ---- barrier arrive: syncthreads drains vmcnt (h in L2); tid0's
      //      agent-release does wbl2 -> chip-visible ----
      __syncthreads();
      if (tid == 0) {
        unsigned a = __hip_atomic_fetch_add(&bar[0], 1u, __ATOMIC_RELEASE,
                                            __HIP_MEMORY_SCOPE_AGENT);
        if (a == NBLKP - 1) {
          __hip_atomic_store(&bar[0], 0u, __ATOMIC_RELAXED,
                             __HIP_MEMORY_SCOPE_AGENT);
          __hip_atomic_fetch_add(&bar[1], 1u, __ATOMIC_RELEASE,
                                 __HIP_MEMORY_SCOPE_AGENT);
        }
      }
    }
    // ---- delayed FC for h_{t-1}: overlapped with barrier slack ----
    if (t > 0) {
      const ushort* hch = hbh + (size_t)((t - 1) & 3) * (BB * HH);
      const ushort* hcl = hbl + (size_t)((t - 1) & 3) * (BB * HH);
      size_t ab = (size_t)(m0f + fr) * HH + wkf * 128 + fk8;
      f32x4 acc = fz;
#pragma unroll
      for (int j = 0; j < 4; ++j) {
        s16x8 afh = *(const s16x8*)&hch[ab + j * 32];
        s16x8 afl = *(const s16x8*)&hcl[ab + j * 32];
        acc = mfma_bf16(afh, fbh[j], acc);
        acc = mfma_bf16(afl, fbh[j], acc);
        acc = mfma_bf16(afh, fbl[j], acc);
      }
      int rb = (lane >> 4) * 4;
      float* rp = red + (wkf * 2 + wo) * 256;
#pragma unroll
      for (int r = 0; r < 4; ++r) rp[(rb + r) * 16 + fr] = acc[r];
      __syncthreads();
      if (tid < 512) {
        int wo2 = tid >> 8, row = (tid >> 4) & 15, col = tid & 15;
        float s = fcbv;
#pragma unroll
        for (int k = 0; k < 8; ++k)
          s += red[(k * 2 + wo2) * 256 + row * 16 + col];
        out[((size_t)(m0f + row) * T + (t - 1)) * OO + o0 + wo2 * 16 + col] = s;
      }
    }
    // ---- barrier wait (bounded spin) + acquire invalidate ----
    if (t < T) {
      if (tid == 0) {
        unsigned tgt = (unsigned)(t + 1);
        unsigned spins = 0;
        while (__hip_atomic_load(&bar[1], __ATOMIC_RELAXED,
                                 __HIP_MEMORY_SCOPE_AGENT) < tgt) {
          __builtin_amdgcn_s_sleep(1);
          if (++spins > SPIN_LIMIT) break;  // hang-proof bail
        }
        (void)__hip_atomic_load(&bar[1], __ATOMIC_ACQUIRE,
                                __HIP_MEMORY_SCOPE_AGENT);
      }
      __syncthreads();
      __builtin_amdgcn_fence(__ATOMIC_ACQUIRE, "agent");
    }
  }
}

extern "C" void kernel_launch(void* const* d_in, const int* in_sizes, int n_in,
                              void* d_out, int out_size, void* d_ws,
                              size_t ws_size, hipStream_t stream) {
  (void)ws_size;
  // ---- order-agnostic input identification by element count ----
  const float *x = nullptr, *Wih = nullptr, *Whh = nullptr, *fcw = nullptr;
  const float *bih = nullptr, *bhh = nullptr, *fcb = nullptr;
  for (int i = 0; i < n_in; ++i) {
    int s = in_sizes[i];
    const float* p = (const float*)d_in[i];
    if (s == BB * EE && !x) x = p;
    else if (s == G4 * EE && !Wih) Wih = p;
    else if (s == G4 * HH && !Whh) Whh = p;
    else if (s == OO * HH && !fcw) fcw = p;
    else if (s == G4 && !bih) bih = p;
    else if (s == G4 && !bhh) bhh = p;  // bias order irrelevant (summed)
    else if (s == OO && !fcb) fcb = p;
  }
  if (!x || !Wih || !Whh || !fcw || !bih || !bhh || !fcb) return;

  // ---- runtime T from out_size ----
  int T = 0;
  if (out_size >= BB * OO && (out_size - HH) % (BB * OO) == 0 &&
      (out_size - HH) / (BB * OO) >= 1) {
    T = (out_size - HH) / (BB * OO);
  } else if (out_size % (BB * OO) == 0) {
    T = out_size / (BB * OO);
  }
  if (T < 1 || T > 16384) return;

  float* out = (float*)d_out;
  float* out_ns = out + (size_t)BB * T * OO;

  // ---- ws layout ----
  ushort* xh = (ushort*)d_ws;
  ushort* xl = xh + (size_t)BB * EE;
  ushort* Wihh = xl + (size_t)BB * EE;
  ushort* Wihl = Wihh + (size_t)G4 * EE;
  ushort* Whhh = Wihl + (size_t)G4 * EE;
  ushort* Whhl = Whhh + (size_t)G4 * HH;
  ushort* fcwh = Whhl + (size_t)G4 * HH;
  ushort* fcwl = fcwh + (size_t)OO * HH;
  ushort* hbh = fcwl + (size_t)OO * HH;               // 4 x B x H (4-deep)
  ushort* hbl = hbh + (size_t)4 * BB * HH;
  float* zbuf = (float*)(hbl + (size_t)4 * BB * HH);  // 128*4096 f32
  unsigned* bar = (unsigned*)(zbuf + (size_t)BB * G4);

  {
    long total = (long)BB * EE + (long)G4 * EE + (long)G4 * HH + (long)OO * HH;
    int cblocks = (int)(total / 4 / 256);  // exact
    hipLaunchKernelGGL(convert_split, dim3(cblocks), dim3(256), 0, stream, x,
                       Wih, Whh, fcw, xh, xl, Wihh, Wihl, Whhh, Whhl, fcwh,
                       fcwl, bar);
  }
  hipLaunchKernelGGL(z_split, dim3(256), dim3(256), 0, stream, xh, xl, Wihh,
                     Wihl, bih, bhh, zbuf);

  static int attr_set = 0;
  if (!attr_set) {
    (void)hipFuncSetAttribute((const void*)persist_kernel,
                              hipFuncAttributeMaxDynamicSharedMemorySize,
                              SMEM_BYTES);
    attr_set = 1;
  }
  // PLAIN launch (graph-capture-safe). 128 blocks x 1 block/CU on a
  // 256-CU chip -> co-residency guaranteed with 2x headroom; the spin
  // bail makes any residual failure a wrong-answer, never a hang.
  hipLaunchKernelGGL(persist_kernel, dim3(NBLKP), dim3(NTHR), SMEM_BYTES,
                     stream, Whhh, Whhl, zbuf, hbh, hbl, fcwh, fcwl, fcb, out,
                     out_ns, bar, T);
}

// Round 3
// 7590.601 us; speedup vs baseline: 1.3019x; 1.3019x over previous
//
#include <hip/hip_runtime.h>
#include <cstdint>
#include <cstddef>

#define BB 128   // batch
#define EE 512   // input dim
#define HH 1024  // hidden
#define G4 4096
#define OO 512   // output dim
#define NBLKP 128    // persistent grid: 128 blocks on 256 CUs -> 2x residency headroom
#define NTHR 512     // 8 waves -> launch_bounds(512,2) -> 256 VGPR budget (MLP!)
#define RED36 36     // reduce-buffer row stride (floats): <=2-way bank conflicts
#define SMEM_BYTES (131072 + BB * RED36 * 4)  // W hi+lo (2x64KB) + red
#define SPIN_LIMIT (1u << 20)  // ~28ms bail: deadlock -> wrong answer, not dead container

typedef float f32x4 __attribute__((ext_vector_type(4)));
typedef short s16x8 __attribute__((ext_vector_type(8)));
typedef __bf16 b16x8 __attribute__((ext_vector_type(8)));

// ---- mfma dispatch: tolerate either short8- or bf16x8-typed builtin ----
template <typename V>
__device__ __forceinline__ auto mfma_try(V a, V b, f32x4 c, int)
    -> decltype(__builtin_amdgcn_mfma_f32_16x16x32_bf16(a, b, c, 0, 0, 0)) {
  return __builtin_amdgcn_mfma_f32_16x16x32_bf16(a, b, c, 0, 0, 0);
}
template <typename V>
__device__ __forceinline__ f32x4 mfma_try(V a, V b, f32x4 c, long) {
  b16x8 ab = __builtin_bit_cast(b16x8, a);
  b16x8 bb = __builtin_bit_cast(b16x8, b);
  return __builtin_amdgcn_mfma_f32_16x16x32_bf16(ab, bb, c, 0, 0, 0);
}
__device__ __forceinline__ f32x4 mfma_bf16(s16x8 a, s16x8 b, f32x4 c) {
  return mfma_try(a, b, c, 0);
}

__device__ __forceinline__ float bf2f(ushort s) {
  unsigned int u = ((unsigned int)s) << 16;
  return __builtin_bit_cast(float, u);
}
__device__ __forceinline__ ushort f2bf(float f) {
  unsigned int u = __builtin_bit_cast(unsigned int, f);
  unsigned int r = (u + 0x7fffu + ((u >> 16) & 1u)) >> 16;
  return (ushort)r;
}
__device__ __forceinline__ float sigm(float x) {
  return 1.0f / (1.0f + __expf(-x));
}

// ======== fp32 -> split bf16 (hi+lo) for x, W_ih, W_hh, fc_w ============
__global__ void __launch_bounds__(256)
convert_split(const float* __restrict__ x, const float* __restrict__ Wih,
              const float* __restrict__ Whh, const float* __restrict__ fcw,
              ushort* __restrict__ xh, ushort* __restrict__ xl,
              ushort* __restrict__ Wihh, ushort* __restrict__ Wihl,
              ushort* __restrict__ Whhh, ushort* __restrict__ Whhl,
              ushort* __restrict__ fcwh, ushort* __restrict__ fcwl,
              unsigned* __restrict__ bar) {
  if (blockIdx.x == 0 && threadIdx.x == 0) { bar[0] = 0u; bar[1] = 0u; }
  const long n0 = (long)BB * EE;
  const long n1 = n0 + (long)G4 * EE;
  const long n2 = n1 + (long)G4 * HH;
  long i = ((long)blockIdx.x * 256 + threadIdx.x) * 4;
  const float* src;
  ushort *dh, *dl;
  long off;
  if (i < n0) {
    src = x; dh = xh; dl = xl; off = i;
  } else if (i < n1) {
    src = Wih; dh = Wihh; dl = Wihl; off = i - n0;
  } else if (i < n2) {
    src = Whh; dh = Whhh; dl = Whhl; off = i - n1;
  } else {
    src = fcw; dh = fcwh; dl = fcwl; off = i - n2;
  }
  float4 v = *(const float4*)&src[off];
  ushort4 h;
  h.x = f2bf(v.x); h.y = f2bf(v.y); h.z = f2bf(v.z); h.w = f2bf(v.w);
  *(ushort4*)&dh[off] = h;
  ushort4 l;
  l.x = f2bf(v.x - bf2f(h.x));
  l.y = f2bf(v.y - bf2f(h.y));
  l.z = f2bf(v.z - bf2f(h.z));
  l.w = f2bf(v.w - bf2f(h.w));
  *(ushort4*)&dl[off] = l;
}

// ========== z = x @ W_ih^T + (b_ih+b_hh) -> zbuf fp32 [B][4H] ===========
__global__ void __launch_bounds__(256)
z_split(const ushort* __restrict__ xh, const ushort* __restrict__ xl,
        const ushort* __restrict__ Wihh, const ushort* __restrict__ Wihl,
        const float* __restrict__ bih, const float* __restrict__ bhh,
        float* __restrict__ zbuf) {
  __shared__ alignas(16) ushort Ah[64][72];
  __shared__ alignas(16) ushort Al[64][72];
  __shared__ alignas(16) ushort Bh[32][72];
  __shared__ alignas(16) ushort Bl[32][72];
  const int tid = threadIdx.x, bid = blockIdx.x;
  const int m0 = (bid >> 7) * 64;
  const int hbase = (bid & 127) * 8;
  const int lane = tid & 63, wave = tid >> 6;
  const int wm = wave & 1, wn = wave >> 1;
  const int fr_row = lane & 15, fr_k = (lane >> 4) * 8;
  const f32x4 fz = {0.f, 0.f, 0.f, 0.f};

  f32x4 a0 = fz, a1 = fz;
  for (int kt = 0; kt < EE / 64; ++kt) {
    for (int i = 0; i < 2; ++i) {
      int idx = tid + i * 256;
      int r = idx >> 3, c8 = (idx & 7) * 8;
      int go = (m0 + r) * EE + kt * 64 + c8;
      *(uint4*)&Ah[r][c8] = *(const uint4*)&xh[go];
      *(uint4*)&Al[r][c8] = *(const uint4*)&xl[go];
    }
    {
      int r = tid >> 3, c8 = (tid & 7) * 8;
      int wrow = (r >> 3) * HH + hbase + (r & 7);
      int go = wrow * EE + kt * 64 + c8;
      *(uint4*)&Bh[r][c8] = *(const uint4*)&Wihh[go];
      *(uint4*)&Bl[r][c8] = *(const uint4*)&Wihl[go];
    }
    __syncthreads();
    for (int kc = 0; kc < 2; ++kc) {
      int ko = kc * 32 + fr_k;
      s16x8 bh = *(const s16x8*)&Bh[wn * 16 + fr_row][ko];
      s16x8 bl = *(const s16x8*)&Bl[wn * 16 + fr_row][ko];
      s16x8 f0h = *(const s16x8*)&Ah[wm * 32 + fr_row][ko];
      s16x8 f0l = *(const s16x8*)&Al[wm * 32 + fr_row][ko];
      s16x8 f1h = *(const s16x8*)&Ah[wm * 32 + 16 + fr_row][ko];
      s16x8 f1l = *(const s16x8*)&Al[wm * 32 + 16 + fr_row][ko];
      a0 = mfma_bf16(f0h, bh, a0);
      a0 = mfma_bf16(f0l, bh, a0);
      a0 = mfma_bf16(f0h, bl, a0);
      a1 = mfma_bf16(f1h, bh, a1);
      a1 = mfma_bf16(f1l, bh, a1);
      a1 = mfma_bf16(f1h, bl, a1);
    }
    __syncthreads();
  }
  int jcol = wn * 16 + fr_row;
  int gc = (jcol >> 3) * HH + hbase + (jcol & 7);
  float bias = bih[gc] + bhh[gc];
  int rbase = wm * 32 + (lane >> 4) * 4;
#pragma unroll
  for (int r = 0; r < 4; ++r) {
    zbuf[(size_t)(m0 + rbase + r) * G4 + gc] = a0[r] + bias;
    zbuf[(size_t)(m0 + rbase + 16 + r) * G4 + gc] = a1[r] + bias;
  }
}

// =====================================================================
// Persistent kernel v3: 128 blocks x 512 thr (8 waves, 256-VGPR budget).
//   Block owns all 128 batch rows x 8 h-cols; its 32 W_hh gate rows
//   (hi+lo, 128 KB) stay in LDS whole kernel, XOR-swizzled.
//   Gates: 8 waves = 8 m-tiles x FULL K (no split, no reduce round);
//   32-iter K-loop fully unrolled -> compiler hoists the 64 independent
//   16B h-loads (immediate offsets off one base) => deep MLP to hide
//   post-L2-inv L3 latency (v2 failure: VGPR=64 => ~no loads in flight).
//   Cell: 2 cells/thread, c in regs. FC in barrier arrive->wait slack.
// =====================================================================
__global__ void __launch_bounds__(NTHR, 2)
persist_kernel(const ushort* __restrict__ Whhh, const ushort* __restrict__ Whhl,
               const float* __restrict__ zbuf,
               ushort* __restrict__ hbh, ushort* __restrict__ hbl,
               const ushort* __restrict__ fcwh, const ushort* __restrict__ fcwl,
               const float* __restrict__ fcb, float* __restrict__ out,
               float* __restrict__ out_ns, unsigned* __restrict__ bar, int T) {
  extern __shared__ char smem[];
  char* WlB = smem + 65536;               // lo plane
  float* red = (float*)(smem + 131072);   // [128][RED36] f32 (also FC 8x256)

  const int tid = threadIdx.x;
  const int hb = blockIdx.x;      // h-slice (8 cols)
  const int lane = tid & 63;
  const int w = tid >> 6;         // 0..7 (= gates m-tile)
  const int fr = lane & 15;
  const int fk8 = (lane >> 4) * 8;
  const int swz = (fr & 7) << 4;
  const f32x4 fz = {0.f, 0.f, 0.f, 0.f};

  // ---- stage W_hh tile into LDS once (swizzled) ----
  for (int i = tid; i < 32 * 128; i += NTHR) {
    int r = i >> 7;                 // local gate row (= g*8+c)
    int cb = (i & 127) * 16;        // byte within row
    int g = r >> 3, c = r & 7;
    size_t go = ((size_t)(g * HH + hb * 8 + c)) * (HH * 2) + (size_t)cb;
    int lofs = r * 2048 + (cb ^ ((r & 7) << 4));
    *(uint4*)(smem + lofs) = *(const uint4*)((const char*)Whhh + go);
    *(uint4*)(WlB + lofs) = *(const uint4*)((const char*)Whhl + go);
  }

  // ---- per-thread cell state + z preload (2 cells/thread) ----
  const int crow = tid >> 3, ccol = tid & 7;  // rows crow and crow+64
  float creg0 = 0.f, creg1 = 0.f;
  size_t zb0 = (size_t)crow * G4 + hb * 8 + ccol;
  size_t zb1 = (size_t)(crow + 64) * G4 + hb * 8 + ccol;
  float zi0 = zbuf[zb0], zf0 = zbuf[zb0 + HH];
  float zg0 = zbuf[zb0 + 2 * HH], zo0 = zbuf[zb0 + 3 * HH];
  float zi1 = zbuf[zb1], zf1 = zbuf[zb1 + HH];
  float zg1 = zbuf[zb1 + 2 * HH], zo1 = zbuf[zb1 + 3 * HH];

  // ---- FC constants: block = 16 out-rows x 32 out-cols; 8 waves =
  //      2 col-halves x 4-way K-split(256). fc_w frags in registers
  //      (all indices compile-time -> stays in VGPRs). ----
  const int m0f = (hb >> 4) * 16;
  const int o0 = (hb & 15) * 32;
  const int wo = w & 1, wkf = w >> 1;
  s16x8 fbh[8], fbl[8];
  {
    size_t base = (size_t)(o0 + wo * 16 + fr) * HH + wkf * 256 + fk8;
#pragma unroll
    for (int j = 0; j < 8; ++j) {
      fbh[j] = *(const s16x8*)&fcwh[base + j * 32];
      fbl[j] = *(const s16x8*)&fcwl[base + j * 32];
    }
  }
  const float fcbv = fcb[o0 + (tid >> 8) * 16 + (tid & 15)];
  __syncthreads();  // W staged

  for (int t = 0; t <= T; ++t) {
    if (t < T) {
      if (t > 0) {
        // ---- gates: h_{t-1} @ Whh^T, full K per wave, unrolled ----
        const ushort* hph = hbh + (size_t)((t - 1) & 3) * (BB * HH);
        const ushort* hpl = hbl + (size_t)((t - 1) & 3) * (BB * HH);
        const ushort* ha = hph + (size_t)(w * 16 + fr) * HH;
        const ushort* la = hpl + (size_t)(w * 16 + fr) * HH;
        f32x4 a0 = fz, a1 = fz;
#pragma unroll
        for (int kt = 0; kt < 32; ++kt) {
          int kk = kt * 32 + fk8;
          s16x8 ah = *(const s16x8*)&ha[kk];
          s16x8 al = *(const s16x8*)&la[kk];
          int sw = (kk * 2) ^ swz;
          int ofs0 = fr * 2048 + sw;
          int ofs1 = (16 + fr) * 2048 + sw;
          s16x8 bh0 = *(const s16x8*)(smem + ofs0);
          s16x8 bl0 = *(const s16x8*)(WlB + ofs0);
          s16x8 bh1 = *(const s16x8*)(smem + ofs1);
          s16x8 bl1 = *(const s16x8*)(WlB + ofs1);
          a0 = mfma_bf16(ah, bh0, a0);
          a0 = mfma_bf16(al, bh0, a0);
          a0 = mfma_bf16(ah, bl0, a0);
          a1 = mfma_bf16(ah, bh1, a1);
          a1 = mfma_bf16(al, bh1, a1);
          a1 = mfma_bf16(ah, bl1, a1);
        }
        // ---- scatter complete gate sums (no cross-wave reduce) ----
        int rrow = w * 16 + (lane >> 4) * 4;
#pragma unroll
        for (int r = 0; r < 4; ++r) {
          red[(rrow + r) * RED36 + fr] = a0[r];
          red[(rrow + r) * RED36 + 16 + fr] = a1[r];
        }
        __syncthreads();
      }
      // ---- LSTM cell (fp32, c in regs), write split-bf16 h_t ----
      {
        float gi0 = zi0, gf0 = zf0, gg0 = zg0, go0 = zo0;
        float gi1 = zi1, gf1 = zf1, gg1 = zg1, go1 = zo1;
        if (t > 0) {
          const float* r0 = red + crow * RED36;
          const float* r1 = red + (crow + 64) * RED36;
          gi0 += r0[ccol];      gi1 += r1[ccol];
          gf0 += r0[8 + ccol];  gf1 += r1[8 + ccol];
          gg0 += r0[16 + ccol]; gg1 += r1[16 + ccol];
          go0 += r0[24 + ccol]; go1 += r1[24 + ccol];
        }
        float iv0 = sigm(gi0), fv0 = sigm(gf0), gv0 = tanhf(gg0), ov0 = sigm(go0);
        float iv1 = sigm(gi1), fv1 = sigm(gf1), gv1 = tanhf(gg1), ov1 = sigm(go1);
        creg0 = fv0 * creg0 + iv0 * gv0;
        creg1 = fv1 * creg1 + iv1 * gv1;
        float hv0 = ov0 * tanhf(creg0);
        float hv1 = ov1 * tanhf(creg1);
        ushort hh0 = f2bf(hv0), hl0 = f2bf(hv0 - bf2f(hh0));
        ushort hh1 = f2bf(hv1), hl1 = f2bf(hv1 - bf2f(hh1));
        size_t hob = (size_t)(t & 3) * (BB * HH) + hb * 8 + ccol;
        hbh[hob + (size_t)crow * HH] = hh0;
        hbl[hob + (size_t)crow * HH] = hl0;
        hbh[hob + (size_t)(crow + 64) * HH] = hh1;
        hbl[hob + (size_t)(crow + 64) * HH] = hl1;
        if (t == T - 1 && crow == 63) out_ns[hb * 8 + ccol] = hv1;
      }
      // ---- barrier arrive: syncthreads drains vmcnt; tid0's agent-
      //      release (wbl2) makes h chip-visible ----
      __syncthreads();
      if (tid == 0) {
        unsigned a = __hip_atomic_fetch_add(&bar[0], 1u, __ATOMIC_RELEASE,
                                            __HIP_MEMORY_SCOPE_AGENT);
        if (a == NBLKP - 1) {
          __hip_atomic_store(&bar[0], 0u, __ATOMIC_RELAXED,
                             __HIP_MEMORY_SCOPE_AGENT);
          __hip_atomic_fetch_add(&bar[1], 1u, __ATOMIC_RELEASE,
                                 __HIP_MEMORY_SCOPE_AGENT);
        }
      }
    }
    // ---- delayed FC for h_{t-1}: overlapped with barrier slack ----
    if (t > 0) {
      const ushort* hch = hbh + (size_t)((t - 1) & 3) * (BB * HH);
      const ushort* hcl = hbl + (size_t)((t - 1) & 3) * (BB * HH);
      size_t ab = (size_t)(m0f + fr) * HH + wkf * 256 + fk8;
      f32x4 acc = fz;
#pragma unroll
      for (int j = 0; j < 8; ++j) {
        s16x8 afh = *(const s16x8*)&hch[ab + j * 32];
        s16x8 afl = *(const s16x8*)&hcl[ab + j * 32];
        acc = mfma_bf16(afh, fbh[j], acc);
        acc = mfma_bf16(afl, fbh[j], acc);
        acc = mfma_bf16(afh, fbl[j], acc);
      }
      int rb = (lane >> 4) * 4;
      float* rp = red + (wkf * 2 + wo) * 256;
#pragma unroll
      for (int r = 0; r < 4; ++r) rp[(rb + r) * 16 + fr] = acc[r];
      __syncthreads();
      {
        int wo2 = tid >> 8, row = (tid >> 4) & 15, col = tid & 15;
        float s = fcbv;
#pragma unroll
        for (int k = 0; k < 4; ++k)
          s += red[(k * 2 + wo2) * 256 + row * 16 + col];
        out[((size_t)(m0f + row) * T + (t - 1)) * OO + o0 + wo2 * 16 + col] = s;
      }
    }
    // ---- barrier wait (bounded spin) + acquire invalidate ----
    if (t < T) {
      if (tid == 0) {
        unsigned tgt = (unsigned)(t + 1);
        unsigned spins = 0;
        while (__hip_atomic_load(&bar[1], __ATOMIC_RELAXED,
                                 __HIP_MEMORY_SCOPE_AGENT) < tgt) {
          __builtin_amdgcn_s_sleep(1);
          if (++spins > SPIN_LIMIT) break;  // hang-proof bail
        }
        (void)__hip_atomic_load(&bar[1], __ATOMIC_ACQUIRE,
                                __HIP_MEMORY_SCOPE_AGENT);
      }
      __syncthreads();
      __builtin_amdgcn_fence(__ATOMIC_ACQUIRE, "agent");
    }
  }
}

extern "C" void kernel_launch(void* const* d_in, const int* in_sizes, int n_in,
                              void* d_out, int out_size, void* d_ws,
                              size_t ws_size, hipStream_t stream) {
  (void)ws_size;
  // ---- order-agnostic input identification by element count ----
  const float *x = nullptr, *Wih = nullptr, *Whh = nullptr, *fcw = nullptr;
  const float *bih = nullptr, *bhh = nullptr, *fcb = nullptr;
  for (int i = 0; i < n_in; ++i) {
    int s = in_sizes[i];
    const float* p = (const float*)d_in[i];
    if (s == BB * EE && !x) x = p;
    else if (s == G4 * EE && !Wih) Wih = p;
    else if (s == G4 * HH && !Whh) Whh = p;
    else if (s == OO * HH && !fcw) fcw = p;
    else if (s == G4 && !bih) bih = p;
    else if (s == G4 && !bhh) bhh = p;  // bias order irrelevant (summed)
    else if (s == OO && !fcb) fcb = p;
  }
  if (!x || !Wih || !Whh || !fcw || !bih || !bhh || !fcb) return;

  // ---- runtime T from out_size ----
  int T = 0;
  if (out_size >= BB * OO && (out_size - HH) % (BB * OO) == 0 &&
      (out_size - HH) / (BB * OO) >= 1) {
    T = (out_size - HH) / (BB * OO);
  } else if (out_size % (BB * OO) == 0) {
    T = out_size / (BB * OO);
  }
  if (T < 1 || T > 16384) return;

  float* out = (float*)d_out;
  float* out_ns = out + (size_t)BB * T * OO;

  // ---- ws layout ----
  ushort* xh = (ushort*)d_ws;
  ushort* xl = xh + (size_t)BB * EE;
  ushort* Wihh = xl + (size_t)BB * EE;
  ushort* Wihl = Wihh + (size_t)G4 * EE;
  ushort* Whhh = Wihl + (size_t)G4 * EE;
  ushort* Whhl = Whhh + (size_t)G4 * HH;
  ushort* fcwh = Whhl + (size_t)G4 * HH;
  ushort* fcwl = fcwh + (size_t)OO * HH;
  ushort* hbh = fcwl + (size_t)OO * HH;               // 4 x B x H (4-deep)
  ushort* hbl = hbh + (size_t)4 * BB * HH;
  float* zbuf = (float*)(hbl + (size_t)4 * BB * HH);  // 128*4096 f32
  unsigned* bar = (unsigned*)(zbuf + (size_t)BB * G4);

  {
    long total = (long)BB * EE + (long)G4 * EE + (long)G4 * HH + (long)OO * HH;
    int cblocks = (int)(total / 4 / 256);  // exact
    hipLaunchKernelGGL(convert_split, dim3(cblocks), dim3(256), 0, stream, x,
                       Wih, Whh, fcw, xh, xl, Wihh, Wihl, Whhh, Whhl, fcwh,
                       fcwl, bar);
  }
  hipLaunchKernelGGL(z_split, dim3(256), dim3(256), 0, stream, xh, xl, Wihh,
                     Wihl, bih, bhh, zbuf);

  static int attr_set = 0;
  if (!attr_set) {
    (void)hipFuncSetAttribute((const void*)persist_kernel,
                              hipFuncAttributeMaxDynamicSharedMemorySize,
                              SMEM_BYTES);
    attr_set = 1;
  }
  // PLAIN launch (graph-capture-safe). 128 blocks, 1 block/CU on 256 CUs
  // -> co-residency with 2x headroom; spin bail guards the residual risk.
  hipLaunchKernelGGL(persist_kernel, dim3(NBLKP), dim3(NTHR), SMEM_BYTES,
                     stream, Whhh, Whhl, zbuf, hbh, hbl, fcwh, fcwl, fcb, out,
                     out_ns, bar, T);
}

// Round 4
// 6862.186 us; speedup vs baseline: 1.4401x; 1.1061x over previous
//
#include <hip/hip_runtime.h>
#include <cstdint>
#include <cstddef>

#define BB 128   // batch
#define EE 512   // input dim
#define HH 1024  // hidden
#define G4 4096
#define OO 512   // output dim
#define NBLKP 128    // persistent grid: 128 blocks on 256 CUs -> 2x residency headroom
#define NTHR 512     // 8 waves -> launch_bounds(512,2) -> 256 VGPR budget
#define RED36 36     // reduce-buffer row stride (floats): <=2-way bank conflicts
#define SMEM_BYTES (131072 + BB * RED36 * 4)  // W hi+lo (2x64KB) + red
#define SPIN_LIMIT (1u << 16)  // bounded spin: deadlock -> wrong answer, not dead container
#define FLAGSTRIDE 16          // flags spaced 64B apart

typedef float f32x4 __attribute__((ext_vector_type(4)));
typedef short s16x8 __attribute__((ext_vector_type(8)));
typedef __bf16 b16x8 __attribute__((ext_vector_type(8)));

// ---- mfma dispatch: tolerate either short8- or bf16x8-typed builtin ----
template <typename V>
__device__ __forceinline__ auto mfma_try(V a, V b, f32x4 c, int)
    -> decltype(__builtin_amdgcn_mfma_f32_16x16x32_bf16(a, b, c, 0, 0, 0)) {
  return __builtin_amdgcn_mfma_f32_16x16x32_bf16(a, b, c, 0, 0, 0);
}
template <typename V>
__device__ __forceinline__ f32x4 mfma_try(V a, V b, f32x4 c, long) {
  b16x8 ab = __builtin_bit_cast(b16x8, a);
  b16x8 bb = __builtin_bit_cast(b16x8, b);
  return __builtin_amdgcn_mfma_f32_16x16x32_bf16(ab, bb, c, 0, 0, 0);
}
__device__ __forceinline__ f32x4 mfma_bf16(s16x8 a, s16x8 b, f32x4 c) {
  return mfma_try(a, b, c, 0);
}

__device__ __forceinline__ float bf2f(ushort s) {
  unsigned int u = ((unsigned int)s) << 16;
  return __builtin_bit_cast(float, u);
}
__device__ __forceinline__ ushort f2bf(float f) {
  unsigned int u = __builtin_bit_cast(unsigned int, f);
  unsigned int r = (u + 0x7fffu + ((u >> 16) & 1u)) >> 16;
  return (ushort)r;
}
__device__ __forceinline__ float sigm(float x) {
  return 1.0f / (1.0f + __expf(-x));
}

// ======== fp32 -> split bf16 (hi+lo) for x, W_ih, W_hh, fc_w ============
__global__ void __launch_bounds__(256)
convert_split(const float* __restrict__ x, const float* __restrict__ Wih,
              const float* __restrict__ Whh, const float* __restrict__ fcw,
              ushort* __restrict__ xh, ushort* __restrict__ xl,
              ushort* __restrict__ Wihh, ushort* __restrict__ Wihl,
              ushort* __restrict__ Whhh, ushort* __restrict__ Whhl,
              ushort* __restrict__ fcwh, ushort* __restrict__ fcwl,
              unsigned* __restrict__ flags) {
  if (blockIdx.x == 0) {
    for (int j = threadIdx.x; j < NBLKP * FLAGSTRIDE; j += 256) flags[j] = 0u;
  }
  const long n0 = (long)BB * EE;
  const long n1 = n0 + (long)G4 * EE;
  const long n2 = n1 + (long)G4 * HH;
  long i = ((long)blockIdx.x * 256 + threadIdx.x) * 4;
  const float* src;
  ushort *dh, *dl;
  long off;
  if (i < n0) {
    src = x; dh = xh; dl = xl; off = i;
  } else if (i < n1) {
    src = Wih; dh = Wihh; dl = Wihl; off = i - n0;
  } else if (i < n2) {
    src = Whh; dh = Whhh; dl = Whhl; off = i - n1;
  } else {
    src = fcw; dh = fcwh; dl = fcwl; off = i - n2;
  }
  float4 v = *(const float4*)&src[off];
  ushort4 h;
  h.x = f2bf(v.x); h.y = f2bf(v.y); h.z = f2bf(v.z); h.w = f2bf(v.w);
  *(ushort4*)&dh[off] = h;
  ushort4 l;
  l.x = f2bf(v.x - bf2f(h.x));
  l.y = f2bf(v.y - bf2f(h.y));
  l.z = f2bf(v.z - bf2f(h.z));
  l.w = f2bf(v.w - bf2f(h.w));
  *(ushort4*)&dl[off] = l;
}

// ========== z = x @ W_ih^T + (b_ih+b_hh) -> zbuf fp32 [B][4H] ===========
__global__ void __launch_bounds__(256)
z_split(const ushort* __restrict__ xh, const ushort* __restrict__ xl,
        const ushort* __restrict__ Wihh, const ushort* __restrict__ Wihl,
        const float* __restrict__ bih, const float* __restrict__ bhh,
        float* __restrict__ zbuf) {
  __shared__ alignas(16) ushort Ah[64][72];
  __shared__ alignas(16) ushort Al[64][72];
  __shared__ alignas(16) ushort Bh[32][72];
  __shared__ alignas(16) ushort Bl[32][72];
  const int tid = threadIdx.x, bid = blockIdx.x;
  const int m0 = (bid >> 7) * 64;
  const int hbase = (bid & 127) * 8;
  const int lane = tid & 63, wave = tid >> 6;
  const int wm = wave & 1, wn = wave >> 1;
  const int fr_row = lane & 15, fr_k = (lane >> 4) * 8;
  const f32x4 fz = {0.f, 0.f, 0.f, 0.f};

  f32x4 a0 = fz, a1 = fz;
  for (int kt = 0; kt < EE / 64; ++kt) {
    for (int i = 0; i < 2; ++i) {
      int idx = tid + i * 256;
      int r = idx >> 3, c8 = (idx & 7) * 8;
      int go = (m0 + r) * EE + kt * 64 + c8;
      *(uint4*)&Ah[r][c8] = *(const uint4*)&xh[go];
      *(uint4*)&Al[r][c8] = *(const uint4*)&xl[go];
    }
    {
      int r = tid >> 3, c8 = (tid & 7) * 8;
      int wrow = (r >> 3) * HH + hbase + (r & 7);
      int go = wrow * EE + kt * 64 + c8;
      *(uint4*)&Bh[r][c8] = *(const uint4*)&Wihh[go];
      *(uint4*)&Bl[r][c8] = *(const uint4*)&Wihl[go];
    }
    __syncthreads();
    for (int kc = 0; kc < 2; ++kc) {
      int ko = kc * 32 + fr_k;
      s16x8 bh = *(const s16x8*)&Bh[wn * 16 + fr_row][ko];
      s16x8 bl = *(const s16x8*)&Bl[wn * 16 + fr_row][ko];
      s16x8 f0h = *(const s16x8*)&Ah[wm * 32 + fr_row][ko];
      s16x8 f0l = *(const s16x8*)&Al[wm * 32 + fr_row][ko];
      s16x8 f1h = *(const s16x8*)&Ah[wm * 32 + 16 + fr_row][ko];
      s16x8 f1l = *(const s16x8*)&Al[wm * 32 + 16 + fr_row][ko];
      a0 = mfma_bf16(f0h, bh, a0);
      a0 = mfma_bf16(f0l, bh, a0);
      a0 = mfma_bf16(f0h, bl, a0);
      a1 = mfma_bf16(f1h, bh, a1);
      a1 = mfma_bf16(f1l, bh, a1);
      a1 = mfma_bf16(f1h, bl, a1);
    }
    __syncthreads();
  }
  int jcol = wn * 16 + fr_row;
  int gc = (jcol >> 3) * HH + hbase + (jcol & 7);
  float bias = bih[gc] + bhh[gc];
  int rbase = wm * 32 + (lane >> 4) * 4;
#pragma unroll
  for (int r = 0; r < 4; ++r) {
    zbuf[(size_t)(m0 + rbase + r) * G4 + gc] = a0[r] + bias;
    zbuf[(size_t)(m0 + rbase + 16 + r) * G4 + gc] = a1[r] + bias;
  }
}

// =====================================================================
// Persistent kernel v4: 128 blocks x 512 thr (8 waves).
//   v3 post-mortem: 128 serialized release-RMWs (each + wbl2) on one
//   word = ~25us/step of barrier cost. v4: FLAG-ARRAY barrier —
//   arrive = release fence + relaxed agent store to own flag (monotone
//   t+1, no reset); wait = 128 threads poll one flag each (no RMW, no
//   contention), then syncthreads + acquire fence.
//   Gates K-loop: explicit double-buffered register prefetch (4-kt
//   chunks) -> >=8 16B loads in flight per wave, guaranteed.
//   W_hh tile (128 KB) LDS-resident, XOR-swizzled; z/c/fc_w in regs;
//   FC for h_{t-1} in the arrive->wait slack; h 4-deep buffered.
// =====================================================================
__global__ void __launch_bounds__(NTHR, 2)
persist_kernel(const ushort* __restrict__ Whhh, const ushort* __restrict__ Whhl,
               const float* __restrict__ zbuf,
               ushort* __restrict__ hbh, ushort* __restrict__ hbl,
               const ushort* __restrict__ fcwh, const ushort* __restrict__ fcwl,
               const float* __restrict__ fcb, float* __restrict__ out,
               float* __restrict__ out_ns, unsigned* __restrict__ flags,
               int T) {
  extern __shared__ char smem[];
  char* WlB = smem + 65536;               // lo plane
  float* red = (float*)(smem + 131072);   // [128][RED36] f32 (also FC 8x256)

  const int tid = threadIdx.x;
  const int hb = blockIdx.x;      // h-slice (8 cols)
  const int lane = tid & 63;
  const int w = tid >> 6;         // 0..7 (= gates m-tile)
  const int fr = lane & 15;
  const int fk8 = (lane >> 4) * 8;
  const int swz = (fr & 7) << 4;
  const f32x4 fz = {0.f, 0.f, 0.f, 0.f};

  // ---- stage W_hh tile into LDS once (swizzled) ----
  for (int i = tid; i < 32 * 128; i += NTHR) {
    int r = i >> 7;                 // local gate row (= g*8+c)
    int cb = (i & 127) * 16;        // byte within row
    int g = r >> 3, c = r & 7;
    size_t go = ((size_t)(g * HH + hb * 8 + c)) * (HH * 2) + (size_t)cb;
    int lofs = r * 2048 + (cb ^ ((r & 7) << 4));
    *(uint4*)(smem + lofs) = *(const uint4*)((const char*)Whhh + go);
    *(uint4*)(WlB + lofs) = *(const uint4*)((const char*)Whhl + go);
  }

  // ---- per-thread cell state + z preload (2 cells/thread) ----
  const int crow = tid >> 3, ccol = tid & 7;  // rows crow and crow+64
  float creg0 = 0.f, creg1 = 0.f;
  size_t zb0 = (size_t)crow * G4 + hb * 8 + ccol;
  size_t zb1 = (size_t)(crow + 64) * G4 + hb * 8 + ccol;
  float zi0 = zbuf[zb0], zf0 = zbuf[zb0 + HH];
  float zg0 = zbuf[zb0 + 2 * HH], zo0 = zbuf[zb0 + 3 * HH];
  float zi1 = zbuf[zb1], zf1 = zbuf[zb1 + HH];
  float zg1 = zbuf[zb1 + 2 * HH], zo1 = zbuf[zb1 + 3 * HH];

  // ---- FC constants: block = 16 out-rows x 32 out-cols; 8 waves =
  //      2 col-halves x 4-way K-split(256). frags in regs (static idx).
  const int m0f = (hb >> 4) * 16;
  const int o0 = (hb & 15) * 32;
  const int wo = w & 1, wkf = w >> 1;
  s16x8 fbh[8], fbl[8];
  {
    size_t base = (size_t)(o0 + wo * 16 + fr) * HH + wkf * 256 + fk8;
#pragma unroll
    for (int j = 0; j < 8; ++j) {
      fbh[j] = *(const s16x8*)&fcwh[base + j * 32];
      fbl[j] = *(const s16x8*)&fcwl[base + j * 32];
    }
  }
  const float fcbv = fcb[o0 + (tid >> 8) * 16 + (tid & 15)];
  __syncthreads();  // W staged

  for (int t = 0; t <= T; ++t) {
    if (t < T) {
      if (t > 0) {
        // ---- gates: h_{t-1} @ Whh^T, full K per wave; explicit
        //      double-buffered register prefetch (4-kt chunks) ----
        const ushort* hph = hbh + (size_t)((t - 1) & 3) * (BB * HH);
        const ushort* hpl = hbl + (size_t)((t - 1) & 3) * (BB * HH);
        const ushort* ha = hph + (size_t)(w * 16 + fr) * HH;
        const ushort* la = hpl + (size_t)(w * 16 + fr) * HH;
        f32x4 a0 = fz, a1 = fz;
        s16x8 pah[4], pal[4];
#pragma unroll
        for (int j = 0; j < 4; ++j) {
          pah[j] = *(const s16x8*)&ha[j * 32 + fk8];
          pal[j] = *(const s16x8*)&la[j * 32 + fk8];
        }
#pragma unroll
        for (int c = 0; c < 8; ++c) {
          s16x8 qah[4], qal[4];
          if (c < 7) {
#pragma unroll
            for (int j = 0; j < 4; ++j) {
              qah[j] = *(const s16x8*)&ha[(c + 1) * 128 + j * 32 + fk8];
              qal[j] = *(const s16x8*)&la[(c + 1) * 128 + j * 32 + fk8];
            }
          }
#pragma unroll
          for (int j = 0; j < 4; ++j) {
            int kk = c * 128 + j * 32 + fk8;
            int sw = (kk * 2) ^ swz;
            int ofs0 = fr * 2048 + sw;
            int ofs1 = (16 + fr) * 2048 + sw;
            s16x8 bh0 = *(const s16x8*)(smem + ofs0);
            s16x8 bl0 = *(const s16x8*)(WlB + ofs0);
            s16x8 bh1 = *(const s16x8*)(smem + ofs1);
            s16x8 bl1 = *(const s16x8*)(WlB + ofs1);
            a0 = mfma_bf16(pah[j], bh0, a0);
            a0 = mfma_bf16(pal[j], bh0, a0);
            a0 = mfma_bf16(pah[j], bl0, a0);
            a1 = mfma_bf16(pah[j], bh1, a1);
            a1 = mfma_bf16(pal[j], bh1, a1);
            a1 = mfma_bf16(pah[j], bl1, a1);
          }
          if (c < 7) {
#pragma unroll
            for (int j = 0; j < 4; ++j) { pah[j] = qah[j]; pal[j] = qal[j]; }
          }
        }
        // ---- scatter complete gate sums ----
        int rrow = w * 16 + (lane >> 4) * 4;
#pragma unroll
        for (int r = 0; r < 4; ++r) {
          red[(rrow + r) * RED36 + fr] = a0[r];
          red[(rrow + r) * RED36 + 16 + fr] = a1[r];
        }
        __syncthreads();
      }
      // ---- LSTM cell (fp32, c in regs), write split-bf16 h_t ----
      {
        float gi0 = zi0, gf0 = zf0, gg0 = zg0, go0 = zo0;
        float gi1 = zi1, gf1 = zf1, gg1 = zg1, go1 = zo1;
        if (t > 0) {
          const float* r0 = red + crow * RED36;
          const float* r1 = red + (crow + 64) * RED36;
          gi0 += r0[ccol];      gi1 += r1[ccol];
          gf0 += r0[8 + ccol];  gf1 += r1[8 + ccol];
          gg0 += r0[16 + ccol]; gg1 += r1[16 + ccol];
          go0 += r0[24 + ccol]; go1 += r1[24 + ccol];
        }
        float iv0 = sigm(gi0), fv0 = sigm(gf0), gv0 = tanhf(gg0), ov0 = sigm(go0);
        float iv1 = sigm(gi1), fv1 = sigm(gf1), gv1 = tanhf(gg1), ov1 = sigm(go1);
        creg0 = fv0 * creg0 + iv0 * gv0;
        creg1 = fv1 * creg1 + iv1 * gv1;
        float hv0 = ov0 * tanhf(creg0);
        float hv1 = ov1 * tanhf(creg1);
        ushort hh0 = f2bf(hv0), hl0 = f2bf(hv0 - bf2f(hh0));
        ushort hh1 = f2bf(hv1), hl1 = f2bf(hv1 - bf2f(hh1));
        size_t hob = (size_t)(t & 3) * (BB * HH) + hb * 8 + ccol;
        hbh[hob + (size_t)crow * HH] = hh0;
        hbl[hob + (size_t)crow * HH] = hl0;
        hbh[hob + (size_t)(crow + 64) * HH] = hh1;
        hbl[hob + (size_t)(crow + 64) * HH] = hl1;
        if (t == T - 1 && crow == 63) out_ns[hb * 8 + ccol] = hv1;
      }
      // ---- barrier arrive: syncthreads drains vmcnt (h complete);
      //      tid0: release fence (wbl2) + relaxed store to OWN flag.
      //      No RMW -> no cross-block serialization. ----
      __syncthreads();
      if (tid == 0) {
        __builtin_amdgcn_fence(__ATOMIC_RELEASE, "agent");
        __hip_atomic_store(&flags[hb * FLAGSTRIDE], (unsigned)(t + 1),
                           __ATOMIC_RELAXED, __HIP_MEMORY_SCOPE_AGENT);
      }
    }
    // ---- delayed FC for h_{t-1}: overlapped with barrier slack ----
    if (t > 0) {
      const ushort* hch = hbh + (size_t)((t - 1) & 3) * (BB * HH);
      const ushort* hcl = hbl + (size_t)((t - 1) & 3) * (BB * HH);
      size_t ab = (size_t)(m0f + fr) * HH + wkf * 256 + fk8;
      f32x4 acc = fz;
#pragma unroll
      for (int j = 0; j < 8; ++j) {
        s16x8 afh = *(const s16x8*)&hch[ab + j * 32];
        s16x8 afl = *(const s16x8*)&hcl[ab + j * 32];
        acc = mfma_bf16(afh, fbh[j], acc);
        acc = mfma_bf16(afl, fbh[j], acc);
        acc = mfma_bf16(afh, fbl[j], acc);
      }
      int rb = (lane >> 4) * 4;
      float* rp = red + (wkf * 2 + wo) * 256;
#pragma unroll
      for (int r = 0; r < 4; ++r) rp[(rb + r) * 16 + fr] = acc[r];
      __syncthreads();
      {
        int wo2 = tid >> 8, row = (tid >> 4) & 15, col = tid & 15;
        float s = fcbv;
#pragma unroll
        for (int k = 0; k < 4; ++k)
          s += red[(k * 2 + wo2) * 256 + row * 16 + col];
        out[((size_t)(m0f + row) * T + (t - 1)) * OO + o0 + wo2 * 16 + col] = s;
      }
    }
    // ---- barrier wait: 128 threads each poll one flag (no RMW);
    //      bounded spin -> never hangs the container ----
    if (t < T) {
      if (tid < NBLKP) {
        unsigned tgt = (unsigned)(t + 1);
        unsigned spins = 0;
        while (__hip_atomic_load(&flags[tid * FLAGSTRIDE], __ATOMIC_RELAXED,
                                 __HIP_MEMORY_SCOPE_AGENT) < tgt) {
          __builtin_amdgcn_s_sleep(1);
          if (++spins > SPIN_LIMIT) break;  // hang-proof bail
        }
      }
      __syncthreads();
      __builtin_amdgcn_fence(__ATOMIC_ACQUIRE, "agent");
    }
  }
}

extern "C" void kernel_launch(void* const* d_in, const int* in_sizes, int n_in,
                              void* d_out, int out_size, void* d_ws,
                              size_t ws_size, hipStream_t stream) {
  (void)ws_size;
  // ---- order-agnostic input identification by element count ----
  const float *x = nullptr, *Wih = nullptr, *Whh = nullptr, *fcw = nullptr;
  const float *bih = nullptr, *bhh = nullptr, *fcb = nullptr;
  for (int i = 0; i < n_in; ++i) {
    int s = in_sizes[i];
    const float* p = (const float*)d_in[i];
    if (s == BB * EE && !x) x = p;
    else if (s == G4 * EE && !Wih) Wih = p;
    else if (s == G4 * HH && !Whh) Whh = p;
    else if (s == OO * HH && !fcw) fcw = p;
    else if (s == G4 && !bih) bih = p;
    else if (s == G4 && !bhh) bhh = p;  // bias order irrelevant (summed)
    else if (s == OO && !fcb) fcb = p;
  }
  if (!x || !Wih || !Whh || !fcw || !bih || !bhh || !fcb) return;

  // ---- runtime T from out_size ----
  int T = 0;
  if (out_size >= BB * OO && (out_size - HH) % (BB * OO) == 0 &&
      (out_size - HH) / (BB * OO) >= 1) {
    T = (out_size - HH) / (BB * OO);
  } else if (out_size % (BB * OO) == 0) {
    T = out_size / (BB * OO);
  }
  if (T < 1 || T > 16384) return;

  float* out = (float*)d_out;
  float* out_ns = out + (size_t)BB * T * OO;

  // ---- ws layout ----
  ushort* xh = (ushort*)d_ws;
  ushort* xl = xh + (size_t)BB * EE;
  ushort* Wihh = xl + (size_t)BB * EE;
  ushort* Wihl = Wihh + (size_t)G4 * EE;
  ushort* Whhh = Wihl + (size_t)G4 * EE;
  ushort* Whhl = Whhh + (size_t)G4 * HH;
  ushort* fcwh = Whhl + (size_t)G4 * HH;
  ushort* fcwl = fcwh + (size_t)OO * HH;
  ushort* hbh = fcwl + (size_t)OO * HH;               // 4 x B x H (4-deep)
  ushort* hbl = hbh + (size_t)4 * BB * HH;
  float* zbuf = (float*)(hbl + (size_t)4 * BB * HH);  // 128*4096 f32
  unsigned* flags = (unsigned*)(zbuf + (size_t)BB * G4);  // 128 x 16 uints

  {
    long total = (long)BB * EE + (long)G4 * EE + (long)G4 * HH + (long)OO * HH;
    int cblocks = (int)(total / 4 / 256);  // exact
    hipLaunchKernelGGL(convert_split, dim3(cblocks), dim3(256), 0, stream, x,
                       Wih, Whh, fcw, xh, xl, Wihh, Wihl, Whhh, Whhl, fcwh,
                       fcwl, flags);
  }
  hipLaunchKernelGGL(z_split, dim3(256), dim3(256), 0, stream, xh, xl, Wihh,
                     Wihl, bih, bhh, zbuf);

  static int attr_set = 0;
  if (!attr_set) {
    (void)hipFuncSetAttribute((const void*)persist_kernel,
                              hipFuncAttributeMaxDynamicSharedMemorySize,
                              SMEM_BYTES);
    attr_set = 1;
  }
  // PLAIN launch (graph-capture-safe). 128 blocks, 1 block/CU on 256 CUs
  // -> co-residency with 2x headroom; spin bail guards the residual risk.
  hipLaunchKernelGGL(persist_kernel, dim3(NBLKP), dim3(NTHR), SMEM_BYTES,
                     stream, Whhh, Whhl, zbuf, hbh, hbl, fcwh, fcwl, fcb, out,
                     out_ns, flags, T);
}

// Round 5
// 5318.091 us; speedup vs baseline: 1.8582x; 1.2903x over previous
//
#include <hip/hip_runtime.h>
#include <cstdint>
#include <cstddef>

#define BB 128   // batch
#define EE 512   // input dim
#define HH 1024  // hidden
#define G4 4096
#define OO 512   // output dim
#define NBLKP 128    // persistent grid: 128 blocks on 256 CUs -> 2x residency headroom
#define NTHR 512     // 8 waves -> launch_bounds(512,2) -> 256 VGPR budget
#define RED36 36     // reduce-buffer row stride (floats): <=2-way bank conflicts
#define SMEM_BYTES (131072 + BB * RED36 * 4)  // W hi+lo (2x64KB) + red
#define SPIN_LIMIT (1u << 16)  // bounded spin: deadlock -> wrong answer, not dead container
#define FLAGSTRIDE 16          // flags spaced 64B apart

typedef float f32x4 __attribute__((ext_vector_type(4)));
typedef short s16x8 __attribute__((ext_vector_type(8)));
typedef __bf16 b16x8 __attribute__((ext_vector_type(8)));

// ---- mfma dispatch: tolerate either short8- or bf16x8-typed builtin ----
template <typename V>
__device__ __forceinline__ auto mfma_try(V a, V b, f32x4 c, int)
    -> decltype(__builtin_amdgcn_mfma_f32_16x16x32_bf16(a, b, c, 0, 0, 0)) {
  return __builtin_amdgcn_mfma_f32_16x16x32_bf16(a, b, c, 0, 0, 0);
}
template <typename V>
__device__ __forceinline__ f32x4 mfma_try(V a, V b, f32x4 c, long) {
  b16x8 ab = __builtin_bit_cast(b16x8, a);
  b16x8 bb = __builtin_bit_cast(b16x8, b);
  return __builtin_amdgcn_mfma_f32_16x16x32_bf16(ab, bb, c, 0, 0, 0);
}
__device__ __forceinline__ f32x4 mfma_bf16(s16x8 a, s16x8 b, f32x4 c) {
  return mfma_try(a, b, c, 0);
}

__device__ __forceinline__ float bf2f(ushort s) {
  unsigned int u = ((unsigned int)s) << 16;
  return __builtin_bit_cast(float, u);
}
__device__ __forceinline__ ushort f2bf(float f) {
  unsigned int u = __builtin_bit_cast(unsigned int, f);
  unsigned int r = (u + 0x7fffu + ((u >> 16) & 1u)) >> 16;
  return (ushort)r;
}
__device__ __forceinline__ float sigm(float x) {
  return 1.0f / (1.0f + __expf(-x));
}
// write-through agent-scope 16-bit store: visible chip-wide once vmcnt
// drains (the compiler's waitcnt before s_barrier) -> no buffer_wbl2 needed
__device__ __forceinline__ void store_short_agent(ushort* p, ushort v) {
  asm volatile("global_store_short %0, %1, off sc1"
               :: "v"(p), "v"((unsigned)v) : "memory");
}

// ======== fp32 -> split bf16 (hi+lo) for x, W_ih, W_hh, fc_w ============
__global__ void __launch_bounds__(256)
convert_split(const float* __restrict__ x, const float* __restrict__ Wih,
              const float* __restrict__ Whh, const float* __restrict__ fcw,
              ushort* __restrict__ xh, ushort* __restrict__ xl,
              ushort* __restrict__ Wihh, ushort* __restrict__ Wihl,
              ushort* __restrict__ Whhh, ushort* __restrict__ Whhl,
              ushort* __restrict__ fcwh, ushort* __restrict__ fcwl,
              unsigned* __restrict__ flags) {
  if (blockIdx.x == 0) {
    for (int j = threadIdx.x; j < NBLKP * FLAGSTRIDE; j += 256) flags[j] = 0u;
  }
  const long n0 = (long)BB * EE;
  const long n1 = n0 + (long)G4 * EE;
  const long n2 = n1 + (long)G4 * HH;
  long i = ((long)blockIdx.x * 256 + threadIdx.x) * 4;
  const float* src;
  ushort *dh, *dl;
  long off;
  if (i < n0) {
    src = x; dh = xh; dl = xl; off = i;
  } else if (i < n1) {
    src = Wih; dh = Wihh; dl = Wihl; off = i - n0;
  } else if (i < n2) {
    src = Whh; dh = Whhh; dl = Whhl; off = i - n1;
  } else {
    src = fcw; dh = fcwh; dl = fcwl; off = i - n2;
  }
  float4 v = *(const float4*)&src[off];
  ushort4 h;
  h.x = f2bf(v.x); h.y = f2bf(v.y); h.z = f2bf(v.z); h.w = f2bf(v.w);
  *(ushort4*)&dh[off] = h;
  ushort4 l;
  l.x = f2bf(v.x - bf2f(h.x));
  l.y = f2bf(v.y - bf2f(h.y));
  l.z = f2bf(v.z - bf2f(h.z));
  l.w = f2bf(v.w - bf2f(h.w));
  *(ushort4*)&dl[off] = l;
}

// ========== z = x @ W_ih^T + (b_ih+b_hh) -> zbuf fp32 [B][4H] ===========
__global__ void __launch_bounds__(256)
z_split(const ushort* __restrict__ xh, const ushort* __restrict__ xl,
        const ushort* __restrict__ Wihh, const ushort* __restrict__ Wihl,
        const float* __restrict__ bih, const float* __restrict__ bhh,
        float* __restrict__ zbuf) {
  __shared__ alignas(16) ushort Ah[64][72];
  __shared__ alignas(16) ushort Al[64][72];
  __shared__ alignas(16) ushort Bh[32][72];
  __shared__ alignas(16) ushort Bl[32][72];
  const int tid = threadIdx.x, bid = blockIdx.x;
  const int m0 = (bid >> 7) * 64;
  const int hbase = (bid & 127) * 8;
  const int lane = tid & 63, wave = tid >> 6;
  const int wm = wave & 1, wn = wave >> 1;
  const int fr_row = lane & 15, fr_k = (lane >> 4) * 8;
  const f32x4 fz = {0.f, 0.f, 0.f, 0.f};

  f32x4 a0 = fz, a1 = fz;
  for (int kt = 0; kt < EE / 64; ++kt) {
    for (int i = 0; i < 2; ++i) {
      int idx = tid + i * 256;
      int r = idx >> 3, c8 = (idx & 7) * 8;
      int go = (m0 + r) * EE + kt * 64 + c8;
      *(uint4*)&Ah[r][c8] = *(const uint4*)&xh[go];
      *(uint4*)&Al[r][c8] = *(const uint4*)&xl[go];
    }
    {
      int r = tid >> 3, c8 = (tid & 7) * 8;
      int wrow = (r >> 3) * HH + hbase + (r & 7);
      int go = wrow * EE + kt * 64 + c8;
      *(uint4*)&Bh[r][c8] = *(const uint4*)&Wihh[go];
      *(uint4*)&Bl[r][c8] = *(const uint4*)&Wihl[go];
    }
    __syncthreads();
    for (int kc = 0; kc < 2; ++kc) {
      int ko = kc * 32 + fr_k;
      s16x8 bh = *(const s16x8*)&Bh[wn * 16 + fr_row][ko];
      s16x8 bl = *(const s16x8*)&Bl[wn * 16 + fr_row][ko];
      s16x8 f0h = *(const s16x8*)&Ah[wm * 32 + fr_row][ko];
      s16x8 f0l = *(const s16x8*)&Al[wm * 32 + fr_row][ko];
      s16x8 f1h = *(const s16x8*)&Ah[wm * 32 + 16 + fr_row][ko];
      s16x8 f1l = *(const s16x8*)&Al[wm * 32 + 16 + fr_row][ko];
      a0 = mfma_bf16(f0h, bh, a0);
      a0 = mfma_bf16(f0l, bh, a0);
      a0 = mfma_bf16(f0h, bl, a0);
      a1 = mfma_bf16(f1h, bh, a1);
      a1 = mfma_bf16(f1l, bh, a1);
      a1 = mfma_bf16(f1h, bl, a1);
    }
    __syncthreads();
  }
  int jcol = wn * 16 + fr_row;
  int gc = (jcol >> 3) * HH + hbase + (jcol & 7);
  float bias = bih[gc] + bhh[gc];
  int rbase = wm * 32 + (lane >> 4) * 4;
#pragma unroll
  for (int r = 0; r < 4; ++r) {
    zbuf[(size_t)(m0 + rbase + r) * G4 + gc] = a0[r] + bias;
    zbuf[(size_t)(m0 + rbase + 16 + r) * G4 + gc] = a1[r] + bias;
  }
}

// =====================================================================
// Persistent kernel v5: fence-minimized.
//   v4 post-mortem: per-step buffer_wbl2 (16/XCD) + buffer_inv (128/XCD)
//   serialized at each L2 = the ~25us/step stall (MfmaUtil 5.4% with MFMA
//   arithmetic exactly matching -> everything else was cache-op wait).
//   v5: h stores are write-through sc1 (inline asm; pipelined; drained by
//   the compiler's vmcnt(0)-before-s_barrier) -> NO release wbl2 at all.
//   h reads stay plain/cached (16 blocks/XCD share L2 fills); the acquire
//   buffer_inv runs on ONE wave per block (1 block/CU; L0 per-CU, L2-inv
//   XCD-wide) between two syncthreads -> 16 invs/XCD/step, was 128+16.
//   Gates K-loop: 3-deep 4-kt chunk prefetch (all indices compile-time).
// =====================================================================
__global__ void __launch_bounds__(NTHR, 2)
persist_kernel(const ushort* __restrict__ Whhh, const ushort* __restrict__ Whhl,
               const float* __restrict__ zbuf,
               ushort* __restrict__ hbh, ushort* __restrict__ hbl,
               const ushort* __restrict__ fcwh, const ushort* __restrict__ fcwl,
               const float* __restrict__ fcb, float* __restrict__ out,
               float* __restrict__ out_ns, unsigned* __restrict__ flags,
               int T) {
  extern __shared__ char smem[];
  char* WlB = smem + 65536;               // lo plane
  float* red = (float*)(smem + 131072);   // [128][RED36] f32 (also FC 8x256)

  const int tid = threadIdx.x;
  const int hb = blockIdx.x;      // h-slice (8 cols)
  const int lane = tid & 63;
  const int w = tid >> 6;         // 0..7 (= gates m-tile)
  const int fr = lane & 15;
  const int fk8 = (lane >> 4) * 8;
  const int swz = (fr & 7) << 4;
  const f32x4 fz = {0.f, 0.f, 0.f, 0.f};

  // ---- stage W_hh tile into LDS once (swizzled) ----
  for (int i = tid; i < 32 * 128; i += NTHR) {
    int r = i >> 7;                 // local gate row (= g*8+c)
    int cb = (i & 127) * 16;        // byte within row
    int g = r >> 3, c = r & 7;
    size_t go = ((size_t)(g * HH + hb * 8 + c)) * (HH * 2) + (size_t)cb;
    int lofs = r * 2048 + (cb ^ ((r & 7) << 4));
    *(uint4*)(smem + lofs) = *(const uint4*)((const char*)Whhh + go);
    *(uint4*)(WlB + lofs) = *(const uint4*)((const char*)Whhl + go);
  }

  // ---- per-thread cell state + z preload (2 cells/thread) ----
  const int crow = tid >> 3, ccol = tid & 7;  // rows crow and crow+64
  float creg0 = 0.f, creg1 = 0.f;
  size_t zb0 = (size_t)crow * G4 + hb * 8 + ccol;
  size_t zb1 = (size_t)(crow + 64) * G4 + hb * 8 + ccol;
  float zi0 = zbuf[zb0], zf0 = zbuf[zb0 + HH];
  float zg0 = zbuf[zb0 + 2 * HH], zo0 = zbuf[zb0 + 3 * HH];
  float zi1 = zbuf[zb1], zf1 = zbuf[zb1 + HH];
  float zg1 = zbuf[zb1 + 2 * HH], zo1 = zbuf[zb1 + 3 * HH];

  // ---- FC constants: block = 16 out-rows x 32 out-cols; 8 waves =
  //      2 col-halves x 4-way K-split(256). frags in regs (static idx).
  const int m0f = (hb >> 4) * 16;
  const int o0 = (hb & 15) * 32;
  const int wo = w & 1, wkf = w >> 1;
  s16x8 fbh[8], fbl[8];
  {
    size_t base = (size_t)(o0 + wo * 16 + fr) * HH + wkf * 256 + fk8;
#pragma unroll
    for (int j = 0; j < 8; ++j) {
      fbh[j] = *(const s16x8*)&fcwh[base + j * 32];
      fbl[j] = *(const s16x8*)&fcwl[base + j * 32];
    }
  }
  const float fcbv = fcb[o0 + (tid >> 8) * 16 + (tid & 15)];
  __syncthreads();  // W staged

  for (int t = 0; t <= T; ++t) {
    if (t < T) {
      if (t > 0) {
        // ---- gates: h_{t-1} @ Whh^T, full K per wave; 3-deep
        //      4-kt-chunk register prefetch (compile-time indices) ----
        const ushort* hph = hbh + (size_t)((t - 1) & 3) * (BB * HH);
        const ushort* hpl = hbl + (size_t)((t - 1) & 3) * (BB * HH);
        const ushort* ha = hph + (size_t)(w * 16 + fr) * HH;
        const ushort* la = hpl + (size_t)(w * 16 + fr) * HH;
        f32x4 a0 = fz, a1 = fz;
        s16x8 ph[3][4], pl[3][4];
#pragma unroll
        for (int j = 0; j < 4; ++j) {
          ph[0][j] = *(const s16x8*)&ha[j * 32 + fk8];
          pl[0][j] = *(const s16x8*)&la[j * 32 + fk8];
        }
#pragma unroll
        for (int j = 0; j < 4; ++j) {
          ph[1][j] = *(const s16x8*)&ha[128 + j * 32 + fk8];
          pl[1][j] = *(const s16x8*)&la[128 + j * 32 + fk8];
        }
#pragma unroll
        for (int c = 0; c < 8; ++c) {
          if (c + 2 < 8) {
#pragma unroll
            for (int j = 0; j < 4; ++j) {
              ph[(c + 2) % 3][j] =
                  *(const s16x8*)&ha[(c + 2) * 128 + j * 32 + fk8];
              pl[(c + 2) % 3][j] =
                  *(const s16x8*)&la[(c + 2) * 128 + j * 32 + fk8];
            }
          }
#pragma unroll
          for (int j = 0; j < 4; ++j) {
            int kk = c * 128 + j * 32 + fk8;
            int sw = (kk * 2) ^ swz;
            int ofs0 = fr * 2048 + sw;
            int ofs1 = (16 + fr) * 2048 + sw;
            s16x8 bh0 = *(const s16x8*)(smem + ofs0);
            s16x8 bl0 = *(const s16x8*)(WlB + ofs0);
            s16x8 bh1 = *(const s16x8*)(smem + ofs1);
            s16x8 bl1 = *(const s16x8*)(WlB + ofs1);
            a0 = mfma_bf16(ph[c % 3][j], bh0, a0);
            a0 = mfma_bf16(pl[c % 3][j], bh0, a0);
            a0 = mfma_bf16(ph[c % 3][j], bl0, a0);
            a1 = mfma_bf16(ph[c % 3][j], bh1, a1);
            a1 = mfma_bf16(pl[c % 3][j], bh1, a1);
            a1 = mfma_bf16(ph[c % 3][j], bl1, a1);
          }
        }
        // ---- scatter complete gate sums ----
        int rrow = w * 16 + (lane >> 4) * 4;
#pragma unroll
        for (int r = 0; r < 4; ++r) {
          red[(rrow + r) * RED36 + fr] = a0[r];
          red[(rrow + r) * RED36 + 16 + fr] = a1[r];
        }
        __syncthreads();
      }
      // ---- LSTM cell (fp32, c in regs); h_t stored via sc1
      //      write-through stores (chip-visible once vmcnt drains) ----
      {
        float gi0 = zi0, gf0 = zf0, gg0 = zg0, go0 = zo0;
        float gi1 = zi1, gf1 = zf1, gg1 = zg1, go1 = zo1;
        if (t > 0) {
          const float* r0 = red + crow * RED36;
          const float* r1 = red + (crow + 64) * RED36;
          gi0 += r0[ccol];      gi1 += r1[ccol];
          gf0 += r0[8 + ccol];  gf1 += r1[8 + ccol];
          gg0 += r0[16 + ccol]; gg1 += r1[16 + ccol];
          go0 += r0[24 + ccol]; go1 += r1[24 + ccol];
        }
        float iv0 = sigm(gi0), fv0 = sigm(gf0), gv0 = tanhf(gg0), ov0 = sigm(go0);
        float iv1 = sigm(gi1), fv1 = sigm(gf1), gv1 = tanhf(gg1), ov1 = sigm(go1);
        creg0 = fv0 * creg0 + iv0 * gv0;
        creg1 = fv1 * creg1 + iv1 * gv1;
        float hv0 = ov0 * tanhf(creg0);
        float hv1 = ov1 * tanhf(creg1);
        ushort hh0 = f2bf(hv0), hl0 = f2bf(hv0 - bf2f(hh0));
        ushort hh1 = f2bf(hv1), hl1 = f2bf(hv1 - bf2f(hh1));
        size_t hob = (size_t)(t & 3) * (BB * HH) + hb * 8 + ccol;
        store_short_agent(hbh + hob + (size_t)crow * HH, hh0);
        store_short_agent(hbl + hob + (size_t)crow * HH, hl0);
        store_short_agent(hbh + hob + (size_t)(crow + 64) * HH, hh1);
        store_short_agent(hbl + hob + (size_t)(crow + 64) * HH, hl1);
        if (t == T - 1 && crow == 63) out_ns[hb * 8 + ccol] = hv1;
      }
      // ---- barrier arrive: syncthreads' compiler vmcnt(0) drains the
      //      sc1 stores (write-through -> globally visible); then flag.
      //      NO release fence / NO wbl2. ----
      __syncthreads();
      if (tid == 0) {
        __hip_atomic_store(&flags[hb * FLAGSTRIDE], (unsigned)(t + 1),
                           __ATOMIC_RELAXED, __HIP_MEMORY_SCOPE_AGENT);
      }
    }
    // ---- delayed FC for h_{t-1}: overlapped with barrier slack
    //      (reads L2-hot lines filled by this step's gates phase) ----
    if (t > 0) {
      const ushort* hch = hbh + (size_t)((t - 1) & 3) * (BB * HH);
      const ushort* hcl = hbl + (size_t)((t - 1) & 3) * (BB * HH);
      size_t ab = (size_t)(m0f + fr) * HH + wkf * 256 + fk8;
      f32x4 acc = fz;
#pragma unroll
      for (int j = 0; j < 8; ++j) {
        s16x8 afh = *(const s16x8*)&hch[ab + j * 32];
        s16x8 afl = *(const s16x8*)&hcl[ab + j * 32];
        acc = mfma_bf16(afh, fbh[j], acc);
        acc = mfma_bf16(afl, fbh[j], acc);
        acc = mfma_bf16(afh, fbl[j], acc);
      }
      int rb = (lane >> 4) * 4;
      float* rp = red + (wkf * 2 + wo) * 256;
#pragma unroll
      for (int r = 0; r < 4; ++r) rp[(rb + r) * 16 + fr] = acc[r];
      __syncthreads();
      {
        int wo2 = tid >> 8, row = (tid >> 4) & 15, col = tid & 15;
        float s = fcbv;
#pragma unroll
        for (int k = 0; k < 4; ++k)
          s += red[(k * 2 + wo2) * 256 + row * 16 + col];
        out[((size_t)(m0f + row) * T + (t - 1)) * OO + o0 + wo2 * 16 + col] = s;
      }
    }
    // ---- barrier wait: poll flags (no RMW, bounded spin), then ONE
    //      acquire-inv per block (wave 0; 1 block/CU so L0 covered,
    //      L2-inv is XCD-wide) between two syncthreads ----
    if (t < T) {
      if (tid < NBLKP) {
        unsigned tgt = (unsigned)(t + 1);
        unsigned spins = 0;
        while (__hip_atomic_load(&flags[tid * FLAGSTRIDE], __ATOMIC_RELAXED,
                                 __HIP_MEMORY_SCOPE_AGENT) < tgt) {
          __builtin_amdgcn_s_sleep(1);
          if (++spins > SPIN_LIMIT) break;  // hang-proof bail
        }
      }
      __syncthreads();
      if (tid < 64) __builtin_amdgcn_fence(__ATOMIC_ACQUIRE, "agent");
      __syncthreads();
    }
  }
}

extern "C" void kernel_launch(void* const* d_in, const int* in_sizes, int n_in,
                              void* d_out, int out_size, void* d_ws,
                              size_t ws_size, hipStream_t stream) {
  (void)ws_size;
  // ---- order-agnostic input identification by element count ----
  const float *x = nullptr, *Wih = nullptr, *Whh = nullptr, *fcw = nullptr;
  const float *bih = nullptr, *bhh = nullptr, *fcb = nullptr;
  for (int i = 0; i < n_in; ++i) {
    int s = in_sizes[i];
    const float* p = (const float*)d_in[i];
    if (s == BB * EE && !x) x = p;
    else if (s == G4 * EE && !Wih) Wih = p;
    else if (s == G4 * HH && !Whh) Whh = p;
    else if (s == OO * HH && !fcw) fcw = p;
    else if (s == G4 && !bih) bih = p;
    else if (s == G4 && !bhh) bhh = p;  // bias order irrelevant (summed)
    else if (s == OO && !fcb) fcb = p;
  }
  if (!x || !Wih || !Whh || !fcw || !bih || !bhh || !fcb) return;

  // ---- runtime T from out_size ----
  int T = 0;
  if (out_size >= BB * OO && (out_size - HH) % (BB * OO) == 0 &&
      (out_size - HH) / (BB * OO) >= 1) {
    T = (out_size - HH) / (BB * OO);
  } else if (out_size % (BB * OO) == 0) {
    T = out_size / (BB * OO);
  }
  if (T < 1 || T > 16384) return;

  float* out = (float*)d_out;
  float* out_ns = out + (size_t)BB * T * OO;

  // ---- ws layout ----
  ushort* xh = (ushort*)d_ws;
  ushort* xl = xh + (size_t)BB * EE;
  ushort* Wihh = xl + (size_t)BB * EE;
  ushort* Wihl = Wihh + (size_t)G4 * EE;
  ushort* Whhh = Wihl + (size_t)G4 * EE;
  ushort* Whhl = Whhh + (size_t)G4 * HH;
  ushort* fcwh = Whhl + (size_t)G4 * HH;
  ushort* fcwl = fcwh + (size_t)OO * HH;
  ushort* hbh = fcwl + (size_t)OO * HH;               // 4 x B x H (4-deep)
  ushort* hbl = hbh + (size_t)4 * BB * HH;
  float* zbuf = (float*)(hbl + (size_t)4 * BB * HH);  // 128*4096 f32
  unsigned* flags = (unsigned*)(zbuf + (size_t)BB * G4);  // 128 x 16 uints

  {
    long total = (long)BB * EE + (long)G4 * EE + (long)G4 * HH + (long)OO * HH;
    int cblocks = (int)(total / 4 / 256);  // exact
    hipLaunchKernelGGL(convert_split, dim3(cblocks), dim3(256), 0, stream, x,
                       Wih, Whh, fcw, xh, xl, Wihh, Wihl, Whhh, Whhl, fcwh,
                       fcwl, flags);
  }
  hipLaunchKernelGGL(z_split, dim3(256), dim3(256), 0, stream, xh, xl, Wihh,
                     Wihl, bih, bhh, zbuf);

  static int attr_set = 0;
  if (!attr_set) {
    (void)hipFuncSetAttribute((const void*)persist_kernel,
                              hipFuncAttributeMaxDynamicSharedMemorySize,
                              SMEM_BYTES);
    attr_set = 1;
  }
  // PLAIN launch (graph-capture-safe). 128 blocks, 1 block/CU on 256 CUs
  // -> co-residency with 2x headroom; spin bail guards the residual risk.
  hipLaunchKernelGGL(persist_kernel, dim3(NBLKP), dim3(NTHR), SMEM_BYTES,
                     stream, Whhh, Whhl, zbuf, hbh, hbl, fcwh, fcwl, fcb, out,
                     out_ns, flags, T);
}

// Round 6
// 3595.628 us; speedup vs baseline: 2.7484x; 1.4790x over previous
//
#include <hip/hip_runtime.h>
#include <cstdint>
#include <cstddef>

#define BB 128   // batch
#define EE 512   // input dim
#define HH 1024  // hidden
#define G4 4096
#define OO 512   // output dim
#define NBLKP 128    // persistent grid: 128 blocks on 256 CUs -> 2x residency headroom
#define NTHR 512     // 8 waves -> launch_bounds(512,2) -> 256 VGPR budget
#define RED36 36     // reduce-buffer row stride (floats): <=2-way bank conflicts
#define SMEM_BYTES (131072 + BB * RED36 * 4)  // W hi+lo (2x64KB) + red
#define SPIN_LIMIT (1u << 16)  // bounded spin: deadlock -> wrong answer, not dead container
#define FLAGSTRIDE 16          // flags spaced 64B apart

typedef float f32x4 __attribute__((ext_vector_type(4)));
typedef short s16x8 __attribute__((ext_vector_type(8)));
typedef __bf16 b16x8 __attribute__((ext_vector_type(8)));

// ---- mfma dispatch: tolerate either short8- or bf16x8-typed builtin ----
template <typename V>
__device__ __forceinline__ auto mfma_try(V a, V b, f32x4 c, int)
    -> decltype(__builtin_amdgcn_mfma_f32_16x16x32_bf16(a, b, c, 0, 0, 0)) {
  return __builtin_amdgcn_mfma_f32_16x16x32_bf16(a, b, c, 0, 0, 0);
}
template <typename V>
__device__ __forceinline__ f32x4 mfma_try(V a, V b, f32x4 c, long) {
  b16x8 ab = __builtin_bit_cast(b16x8, a);
  b16x8 bb = __builtin_bit_cast(b16x8, b);
  return __builtin_amdgcn_mfma_f32_16x16x32_bf16(ab, bb, c, 0, 0, 0);
}
__device__ __forceinline__ f32x4 mfma_bf16(s16x8 a, s16x8 b, f32x4 c) {
  return mfma_try(a, b, c, 0);
}

__device__ __forceinline__ float bf2f(ushort s) {
  unsigned int u = ((unsigned int)s) << 16;
  return __builtin_bit_cast(float, u);
}
__device__ __forceinline__ ushort f2bf(float f) {
  unsigned int u = __builtin_bit_cast(unsigned int, f);
  unsigned int r = (u + 0x7fffu + ((u >> 16) & 1u)) >> 16;
  return (ushort)r;
}
__device__ __forceinline__ float sigm(float x) {
  return 1.0f / (1.0f + __expf(-x));
}
// write-through agent-scope 16-bit store: with the block-major h layout
// these are wave-contiguous -> coalesce to FULL 64B lines (no HBM RMW)
__device__ __forceinline__ void store_short_agent(ushort* p, ushort v) {
  asm volatile("global_store_short %0, %1, off sc1"
               :: "v"(p), "v"((unsigned)v) : "memory");
}

// ======== fp32 -> split bf16 (hi+lo) for x, W_ih, W_hh, fc_w ============
__global__ void __launch_bounds__(256)
convert_split(const float* __restrict__ x, const float* __restrict__ Wih,
              const float* __restrict__ Whh, const float* __restrict__ fcw,
              ushort* __restrict__ xh, ushort* __restrict__ xl,
              ushort* __restrict__ Wihh, ushort* __restrict__ Wihl,
              ushort* __restrict__ Whhh, ushort* __restrict__ Whhl,
              ushort* __restrict__ fcwh, ushort* __restrict__ fcwl,
              unsigned* __restrict__ flags) {
  if (blockIdx.x == 0) {
    for (int j = threadIdx.x; j < NBLKP * FLAGSTRIDE; j += 256) flags[j] = 0u;
  }
  const long n0 = (long)BB * EE;
  const long n1 = n0 + (long)G4 * EE;
  const long n2 = n1 + (long)G4 * HH;
  long i = ((long)blockIdx.x * 256 + threadIdx.x) * 4;
  const float* src;
  ushort *dh, *dl;
  long off;
  if (i < n0) {
    src = x; dh = xh; dl = xl; off = i;
  } else if (i < n1) {
    src = Wih; dh = Wihh; dl = Wihl; off = i - n0;
  } else if (i < n2) {
    src = Whh; dh = Whhh; dl = Whhl; off = i - n1;
  } else {
    src = fcw; dh = fcwh; dl = fcwl; off = i - n2;
  }
  float4 v = *(const float4*)&src[off];
  ushort4 h;
  h.x = f2bf(v.x); h.y = f2bf(v.y); h.z = f2bf(v.z); h.w = f2bf(v.w);
  *(ushort4*)&dh[off] = h;
  ushort4 l;
  l.x = f2bf(v.x - bf2f(h.x));
  l.y = f2bf(v.y - bf2f(h.y));
  l.z = f2bf(v.z - bf2f(h.z));
  l.w = f2bf(v.w - bf2f(h.w));
  *(ushort4*)&dl[off] = l;
}

// ========== z = x @ W_ih^T + (b_ih+b_hh) -> zbuf fp32 [B][4H] ===========
__global__ void __launch_bounds__(256)
z_split(const ushort* __restrict__ xh, const ushort* __restrict__ xl,
        const ushort* __restrict__ Wihh, const ushort* __restrict__ Wihl,
        const float* __restrict__ bih, const float* __restrict__ bhh,
        float* __restrict__ zbuf) {
  __shared__ alignas(16) ushort Ah[64][72];
  __shared__ alignas(16) ushort Al[64][72];
  __shared__ alignas(16) ushort Bh[32][72];
  __shared__ alignas(16) ushort Bl[32][72];
  const int tid = threadIdx.x, bid = blockIdx.x;
  const int m0 = (bid >> 7) * 64;
  const int hbase = (bid & 127) * 8;
  const int lane = tid & 63, wave = tid >> 6;
  const int wm = wave & 1, wn = wave >> 1;
  const int fr_row = lane & 15, fr_k = (lane >> 4) * 8;
  const f32x4 fz = {0.f, 0.f, 0.f, 0.f};

  f32x4 a0 = fz, a1 = fz;
  for (int kt = 0; kt < EE / 64; ++kt) {
    for (int i = 0; i < 2; ++i) {
      int idx = tid + i * 256;
      int r = idx >> 3, c8 = (idx & 7) * 8;
      int go = (m0 + r) * EE + kt * 64 + c8;
      *(uint4*)&Ah[r][c8] = *(const uint4*)&xh[go];
      *(uint4*)&Al[r][c8] = *(const uint4*)&xl[go];
    }
    {
      int r = tid >> 3, c8 = (tid & 7) * 8;
      int wrow = (r >> 3) * HH + hbase + (r & 7);
      int go = wrow * EE + kt * 64 + c8;
      *(uint4*)&Bh[r][c8] = *(const uint4*)&Wihh[go];
      *(uint4*)&Bl[r][c8] = *(const uint4*)&Wihl[go];
    }
    __syncthreads();
    for (int kc = 0; kc < 2; ++kc) {
      int ko = kc * 32 + fr_k;
      s16x8 bh = *(const s16x8*)&Bh[wn * 16 + fr_row][ko];
      s16x8 bl = *(const s16x8*)&Bl[wn * 16 + fr_row][ko];
      s16x8 f0h = *(const s16x8*)&Ah[wm * 32 + fr_row][ko];
      s16x8 f0l = *(const s16x8*)&Al[wm * 32 + fr_row][ko];
      s16x8 f1h = *(const s16x8*)&Ah[wm * 32 + 16 + fr_row][ko];
      s16x8 f1l = *(const s16x8*)&Al[wm * 32 + 16 + fr_row][ko];
      a0 = mfma_bf16(f0h, bh, a0);
      a0 = mfma_bf16(f0l, bh, a0);
      a0 = mfma_bf16(f0h, bl, a0);
      a1 = mfma_bf16(f1h, bh, a1);
      a1 = mfma_bf16(f1l, bh, a1);
      a1 = mfma_bf16(f1h, bl, a1);
    }
    __syncthreads();
  }
  int jcol = wn * 16 + fr_row;
  int gc = (jcol >> 3) * HH + hbase + (jcol & 7);
  float bias = bih[gc] + bhh[gc];
  int rbase = wm * 32 + (lane >> 4) * 4;
#pragma unroll
  for (int r = 0; r < 4; ++r) {
    zbuf[(size_t)(m0 + rbase + r) * G4 + gc] = a0[r] + bias;
    zbuf[(size_t)(m0 + rbase + 16 + r) * G4 + gc] = a1[r] + bias;
  }
}

// =====================================================================
// Persistent kernel v6: block-major h layout.
//   v5 post-mortem: FETCH 2.1MB/step (11x working set) = HBM read-
//   modify-write caused by sc1 write-through of 16B PARTIAL cachelines
//   (4 blocks shared each 64B line of row-major h). v6 re-layouts h as
//   [slot][kblock=hb][row][8]: each block's h output = one contiguous
//   2KB region, wave-contiguous 2B stores -> full-line write-through,
//   no RMW. Readers: lane's 16B load = [kb][row][8] cell at
//   kb*1024+row*8; chunk offsets compile-time off one base.
//   Everything else from v5: flag-array barrier (no RMW), one
//   acquire-inv per block, FC in arrive->wait slack, W_hh LDS-resident.
// =====================================================================
__global__ void __launch_bounds__(NTHR, 2)
persist_kernel(const ushort* __restrict__ Whhh, const ushort* __restrict__ Whhl,
               const float* __restrict__ zbuf,
               ushort* __restrict__ hbh, ushort* __restrict__ hbl,
               const ushort* __restrict__ fcwh, const ushort* __restrict__ fcwl,
               const float* __restrict__ fcb, float* __restrict__ out,
               float* __restrict__ out_ns, unsigned* __restrict__ flags,
               int T) {
  extern __shared__ char smem[];
  char* WlB = smem + 65536;               // lo plane
  float* red = (float*)(smem + 131072);   // [128][RED36] f32 (also FC 8x256)

  const int tid = threadIdx.x;
  const int hb = blockIdx.x;      // h-slice (8 cols) = k-block it produces
  const int lane = tid & 63;
  const int w = tid >> 6;         // 0..7 (= gates m-tile)
  const int fr = lane & 15;
  const int fk8 = (lane >> 4) * 8;
  const int swz = (fr & 7) << 4;
  const f32x4 fz = {0.f, 0.f, 0.f, 0.f};

  // ---- stage W_hh tile into LDS once (swizzled) ----
  for (int i = tid; i < 32 * 128; i += NTHR) {
    int r = i >> 7;                 // local gate row (= g*8+c)
    int cb = (i & 127) * 16;        // byte within row
    int g = r >> 3, c = r & 7;
    size_t go = ((size_t)(g * HH + hb * 8 + c)) * (HH * 2) + (size_t)cb;
    int lofs = r * 2048 + (cb ^ ((r & 7) << 4));
    *(uint4*)(smem + lofs) = *(const uint4*)((const char*)Whhh + go);
    *(uint4*)(WlB + lofs) = *(const uint4*)((const char*)Whhl + go);
  }

  // ---- per-thread cell state + z preload (2 cells/thread) ----
  const int crow = tid >> 3, ccol = tid & 7;  // rows crow and crow+64
  float creg0 = 0.f, creg1 = 0.f;
  size_t zb0 = (size_t)crow * G4 + hb * 8 + ccol;
  size_t zb1 = (size_t)(crow + 64) * G4 + hb * 8 + ccol;
  float zi0 = zbuf[zb0], zf0 = zbuf[zb0 + HH];
  float zg0 = zbuf[zb0 + 2 * HH], zo0 = zbuf[zb0 + 3 * HH];
  float zi1 = zbuf[zb1], zf1 = zbuf[zb1 + HH];
  float zg1 = zbuf[zb1 + 2 * HH], zo1 = zbuf[zb1 + 3 * HH];

  // ---- FC constants: block = 16 out-rows x 32 out-cols; 8 waves =
  //      2 col-halves x 4-way K-split(256). frags in regs (static idx).
  const int m0f = (hb >> 4) * 16;
  const int o0 = (hb & 15) * 32;
  const int wo = w & 1, wkf = w >> 1;
  s16x8 fbh[8], fbl[8];
  {
    size_t base = (size_t)(o0 + wo * 16 + fr) * HH + wkf * 256 + fk8;
#pragma unroll
    for (int j = 0; j < 8; ++j) {
      fbh[j] = *(const s16x8*)&fcwh[base + j * 32];
      fbl[j] = *(const s16x8*)&fcwl[base + j * 32];
    }
  }
  const float fcbv = fcb[o0 + (tid >> 8) * 16 + (tid & 15)];
  __syncthreads();  // W staged

  for (int t = 0; t <= T; ++t) {
    if (t < T) {
      if (t > 0) {
        // ---- gates: h_{t-1} @ Whh^T, full K per wave; 3-deep
        //      4-kb-chunk register prefetch. Block-major layout:
        //      lane base = row*8 + q*1024, chunk offset (c*16+j*4)*1024
        const ushort* hph = hbh + (size_t)((t - 1) & 3) * (BB * HH);
        const ushort* hpl = hbl + (size_t)((t - 1) & 3) * (BB * HH);
        const ushort* ha =
            hph + (size_t)(w * 16 + fr) * 8 + (size_t)(lane >> 4) * (BB * 8);
        const ushort* la =
            hpl + (size_t)(w * 16 + fr) * 8 + (size_t)(lane >> 4) * (BB * 8);
        f32x4 a0 = fz, a1 = fz;
        s16x8 ph[3][4], pl[3][4];
#pragma unroll
        for (int j = 0; j < 4; ++j) {
          ph[0][j] = *(const s16x8*)&ha[(j * 4) * (BB * 8)];
          pl[0][j] = *(const s16x8*)&la[(j * 4) * (BB * 8)];
        }
#pragma unroll
        for (int j = 0; j < 4; ++j) {
          ph[1][j] = *(const s16x8*)&ha[(16 + j * 4) * (BB * 8)];
          pl[1][j] = *(const s16x8*)&la[(16 + j * 4) * (BB * 8)];
        }
#pragma unroll
        for (int c = 0; c < 8; ++c) {
          if (c + 2 < 8) {
#pragma unroll
            for (int j = 0; j < 4; ++j) {
              ph[(c + 2) % 3][j] =
                  *(const s16x8*)&ha[((c + 2) * 16 + j * 4) * (BB * 8)];
              pl[(c + 2) % 3][j] =
                  *(const s16x8*)&la[((c + 2) * 16 + j * 4) * (BB * 8)];
            }
          }
#pragma unroll
          for (int j = 0; j < 4; ++j) {
            int kk = c * 128 + j * 32 + fk8;
            int sw = (kk * 2) ^ swz;
            int ofs0 = fr * 2048 + sw;
            int ofs1 = (16 + fr) * 2048 + sw;
            s16x8 bh0 = *(const s16x8*)(smem + ofs0);
            s16x8 bl0 = *(const s16x8*)(WlB + ofs0);
            s16x8 bh1 = *(const s16x8*)(smem + ofs1);
            s16x8 bl1 = *(const s16x8*)(WlB + ofs1);
            a0 = mfma_bf16(ph[c % 3][j], bh0, a0);
            a0 = mfma_bf16(pl[c % 3][j], bh0, a0);
            a0 = mfma_bf16(ph[c % 3][j], bl0, a0);
            a1 = mfma_bf16(ph[c % 3][j], bh1, a1);
            a1 = mfma_bf16(pl[c % 3][j], bh1, a1);
            a1 = mfma_bf16(ph[c % 3][j], bl1, a1);
          }
        }
        // ---- scatter complete gate sums ----
        int rrow = w * 16 + (lane >> 4) * 4;
#pragma unroll
        for (int r = 0; r < 4; ++r) {
          red[(rrow + r) * RED36 + fr] = a0[r];
          red[(rrow + r) * RED36 + 16 + fr] = a1[r];
        }
        __syncthreads();
      }
      // ---- LSTM cell (fp32, c in regs); h_t stored block-major:
      //      offsets tid and 512+tid -> wave-contiguous full lines ----
      {
        float gi0 = zi0, gf0 = zf0, gg0 = zg0, go0 = zo0;
        float gi1 = zi1, gf1 = zf1, gg1 = zg1, go1 = zo1;
        if (t > 0) {
          const float* r0 = red + crow * RED36;
          const float* r1 = red + (crow + 64) * RED36;
          gi0 += r0[ccol];      gi1 += r1[ccol];
          gf0 += r0[8 + ccol];  gf1 += r1[8 + ccol];
          gg0 += r0[16 + ccol]; gg1 += r1[16 + ccol];
          go0 += r0[24 + ccol]; go1 += r1[24 + ccol];
        }
        float iv0 = sigm(gi0), fv0 = sigm(gf0), gv0 = tanhf(gg0), ov0 = sigm(go0);
        float iv1 = sigm(gi1), fv1 = sigm(gf1), gv1 = tanhf(gg1), ov1 = sigm(go1);
        creg0 = fv0 * creg0 + iv0 * gv0;
        creg1 = fv1 * creg1 + iv1 * gv1;
        float hv0 = ov0 * tanhf(creg0);
        float hv1 = ov1 * tanhf(creg1);
        ushort hh0 = f2bf(hv0), hl0 = f2bf(hv0 - bf2f(hh0));
        ushort hh1 = f2bf(hv1), hl1 = f2bf(hv1 - bf2f(hh1));
        size_t hob = (size_t)(t & 3) * (BB * HH) + (size_t)hb * (BB * 8);
        store_short_agent(hbh + hob + tid, hh0);         // row crow
        store_short_agent(hbl + hob + tid, hl0);
        store_short_agent(hbh + hob + 512 + tid, hh1);   // row crow+64
        store_short_agent(hbl + hob + 512 + tid, hl1);
        if (t == T - 1 && crow == 63) out_ns[hb * 8 + ccol] = hv1;
      }
      // ---- barrier arrive: syncthreads' vmcnt(0) drains the sc1
      //      stores (full-line write-through, globally visible); flag.
      __syncthreads();
      if (tid == 0) {
        __hip_atomic_store(&flags[hb * FLAGSTRIDE], (unsigned)(t + 1),
                           __ATOMIC_RELAXED, __HIP_MEMORY_SCOPE_AGENT);
      }
    }
    // ---- delayed FC for h_{t-1}: overlapped with barrier slack
    //      (reads lines this step's gates phase already pulled) ----
    if (t > 0) {
      const ushort* hch = hbh + (size_t)((t - 1) & 3) * (BB * HH);
      const ushort* hcl = hbl + (size_t)((t - 1) & 3) * (BB * HH);
      const ushort* hca =
          hch + (size_t)(m0f + fr) * 8 + (size_t)(lane >> 4) * (BB * 8);
      const ushort* hcb =
          hcl + (size_t)(m0f + fr) * 8 + (size_t)(lane >> 4) * (BB * 8);
      f32x4 acc = fz;
#pragma unroll
      for (int j = 0; j < 8; ++j) {
        s16x8 afh = *(const s16x8*)&hca[(wkf * 32 + j * 4) * (BB * 8)];
        s16x8 afl = *(const s16x8*)&hcb[(wkf * 32 + j * 4) * (BB * 8)];
        acc = mfma_bf16(afh, fbh[j], acc);
        acc = mfma_bf16(afl, fbh[j], acc);
        acc = mfma_bf16(afh, fbl[j], acc);
      }
      int rb = (lane >> 4) * 4;
      float* rp = red + (wkf * 2 + wo) * 256;
#pragma unroll
      for (int r = 0; r < 4; ++r) rp[(rb + r) * 16 + fr] = acc[r];
      __syncthreads();
      {
        int wo2 = tid >> 8, row = (tid >> 4) & 15, col = tid & 15;
        float s = fcbv;
#pragma unroll
        for (int k = 0; k < 4; ++k)
          s += red[(k * 2 + wo2) * 256 + row * 16 + col];
        out[((size_t)(m0f + row) * T + (t - 1)) * OO + o0 + wo2 * 16 + col] = s;
      }
    }
    // ---- barrier wait: poll flags (no RMW, bounded spin), then ONE
    //      acquire-inv per block (wave 0; 1 block/CU -> covers L0+L2)
    if (t < T) {
      if (tid < NBLKP) {
        unsigned tgt = (unsigned)(t + 1);
        unsigned spins = 0;
        while (__hip_atomic_load(&flags[tid * FLAGSTRIDE], __ATOMIC_RELAXED,
                                 __HIP_MEMORY_SCOPE_AGENT) < tgt) {
          __builtin_amdgcn_s_sleep(1);
          if (++spins > SPIN_LIMIT) break;  // hang-proof bail
        }
      }
      __syncthreads();
      if (tid < 64) __builtin_amdgcn_fence(__ATOMIC_ACQUIRE, "agent");
      __syncthreads();
    }
  }
}

extern "C" void kernel_launch(void* const* d_in, const int* in_sizes, int n_in,
                              void* d_out, int out_size, void* d_ws,
                              size_t ws_size, hipStream_t stream) {
  (void)ws_size;
  // ---- order-agnostic input identification by element count ----
  const float *x = nullptr, *Wih = nullptr, *Whh = nullptr, *fcw = nullptr;
  const float *bih = nullptr, *bhh = nullptr, *fcb = nullptr;
  for (int i = 0; i < n_in; ++i) {
    int s = in_sizes[i];
    const float* p = (const float*)d_in[i];
    if (s == BB * EE && !x) x = p;
    else if (s == G4 * EE && !Wih) Wih = p;
    else if (s == G4 * HH && !Whh) Whh = p;
    else if (s == OO * HH && !fcw) fcw = p;
    else if (s == G4 && !bih) bih = p;
    else if (s == G4 && !bhh) bhh = p;  // bias order irrelevant (summed)
    else if (s == OO && !fcb) fcb = p;
  }
  if (!x || !Wih || !Whh || !fcw || !bih || !bhh || !fcb) return;

  // ---- runtime T from out_size ----
  int T = 0;
  if (out_size >= BB * OO && (out_size - HH) % (BB * OO) == 0 &&
      (out_size - HH) / (BB * OO) >= 1) {
    T = (out_size - HH) / (BB * OO);
  } else if (out_size % (BB * OO) == 0) {
    T = out_size / (BB * OO);
  }
  if (T < 1 || T > 16384) return;

  float* out = (float*)d_out;
  float* out_ns = out + (size_t)BB * T * OO;

  // ---- ws layout ----
  ushort* xh = (ushort*)d_ws;
  ushort* xl = xh + (size_t)BB * EE;
  ushort* Wihh = xl + (size_t)BB * EE;
  ushort* Wihl = Wihh + (size_t)G4 * EE;
  ushort* Whhh = Wihl + (size_t)G4 * EE;
  ushort* Whhl = Whhh + (size_t)G4 * HH;
  ushort* fcwh = Whhl + (size_t)G4 * HH;
  ushort* fcwl = fcwh + (size_t)OO * HH;
  ushort* hbh = fcwl + (size_t)OO * HH;               // 4 x B x H (4-deep)
  ushort* hbl = hbh + (size_t)4 * BB * HH;
  float* zbuf = (float*)(hbl + (size_t)4 * BB * HH);  // 128*4096 f32
  unsigned* flags = (unsigned*)(zbuf + (size_t)BB * G4);  // 128 x 16 uints

  {
    long total = (long)BB * EE + (long)G4 * EE + (long)G4 * HH + (long)OO * HH;
    int cblocks = (int)(total / 4 / 256);  // exact
    hipLaunchKernelGGL(convert_split, dim3(cblocks), dim3(256), 0, stream, x,
                       Wih, Whh, fcw, xh, xl, Wihh, Wihl, Whhh, Whhl, fcwh,
                       fcwl, flags);
  }
  hipLaunchKernelGGL(z_split, dim3(256), dim3(256), 0, stream, xh, xl, Wihh,
                     Wihl, bih, bhh, zbuf);

  static int attr_set = 0;
  if (!attr_set) {
    (void)hipFuncSetAttribute((const void*)persist_kernel,
                              hipFuncAttributeMaxDynamicSharedMemorySize,
                              SMEM_BYTES);
    attr_set = 1;
  }
  // PLAIN launch (graph-capture-safe). 128 blocks, 1 block/CU on 256 CUs
  // -> co-residency with 2x headroom; spin bail guards the residual risk.
  hipLaunchKernelGGL(persist_kernel, dim3(NBLKP), dim3(NTHR), SMEM_BYTES,
                     stream, Whhh, Whhl, zbuf, hbh, hbl, fcwh, fcwl, fcb, out,
                     out_ns, flags, T);
}

// Round 7
// 2541.504 us; speedup vs baseline: 3.8884x; 1.4148x over previous
//
#include <hip/hip_runtime.h>
#include <cstdint>
#include <cstddef>

#define BB 128   // batch
#define EE 512   // input dim
#define HH 1024  // hidden
#define G4 4096
#define OO 512   // output dim
#define NBLKP 128    // persistent grid: 128 blocks on 256 CUs -> 2x residency headroom
#define NTHR 512     // 8 waves -> launch_bounds(512,2) -> 256 VGPR budget
#define RED36 36     // reduce-buffer row stride (floats): <=2-way bank conflicts
#define SMEM_BYTES (131072 + BB * RED36 * 4)  // W hi+lo (2x64KB) + red
#define SPIN_LIMIT (1u << 16)  // bounded spin: deadlock -> wrong answer, not dead container
#define FLAGSTRIDE 16          // flags spaced 64B apart

typedef float f32x4 __attribute__((ext_vector_type(4)));
typedef short s16x8 __attribute__((ext_vector_type(8)));
typedef __bf16 b16x8 __attribute__((ext_vector_type(8)));

// ---- mfma dispatch: tolerate either short8- or bf16x8-typed builtin ----
template <typename V>
__device__ __forceinline__ auto mfma_try(V a, V b, f32x4 c, int)
    -> decltype(__builtin_amdgcn_mfma_f32_16x16x32_bf16(a, b, c, 0, 0, 0)) {
  return __builtin_amdgcn_mfma_f32_16x16x32_bf16(a, b, c, 0, 0, 0);
}
template <typename V>
__device__ __forceinline__ f32x4 mfma_try(V a, V b, f32x4 c, long) {
  b16x8 ab = __builtin_bit_cast(b16x8, a);
  b16x8 bb = __builtin_bit_cast(b16x8, b);
  return __builtin_amdgcn_mfma_f32_16x16x32_bf16(ab, bb, c, 0, 0, 0);
}
__device__ __forceinline__ f32x4 mfma_bf16(s16x8 a, s16x8 b, f32x4 c) {
  return mfma_try(a, b, c, 0);
}

__device__ __forceinline__ float bf2f(ushort s) {
  unsigned int u = ((unsigned int)s) << 16;
  return __builtin_bit_cast(float, u);
}
__device__ __forceinline__ ushort f2bf(float f) {
  unsigned int u = __builtin_bit_cast(unsigned int, f);
  unsigned int r = (u + 0x7fffu + ((u >> 16) & 1u)) >> 16;
  return (ushort)r;
}
__device__ __forceinline__ float sigm(float x) {
  return 1.0f / (1.0f + __expf(-x));
}
// write-through agent-scope 16-bit store: with the block-major h layout
// these are wave-contiguous -> coalesce to FULL 64B lines (no HBM RMW)
__device__ __forceinline__ void store_short_agent(ushort* p, ushort v) {
  asm volatile("global_store_short %0, %1, off sc1"
               :: "v"(p), "v"((unsigned)v) : "memory");
}

// ======== fp32 -> split bf16 (hi+lo) for x, W_ih, W_hh, fc_w ============
__global__ void __launch_bounds__(256)
convert_split(const float* __restrict__ x, const float* __restrict__ Wih,
              const float* __restrict__ Whh, const float* __restrict__ fcw,
              ushort* __restrict__ xh, ushort* __restrict__ xl,
              ushort* __restrict__ Wihh, ushort* __restrict__ Wihl,
              ushort* __restrict__ Whhh, ushort* __restrict__ Whhl,
              ushort* __restrict__ fcwh, ushort* __restrict__ fcwl,
              unsigned* __restrict__ flags) {
  if (blockIdx.x == 0) {
    for (int j = threadIdx.x; j < NBLKP * FLAGSTRIDE; j += 256) flags[j] = 0u;
  }
  const long n0 = (long)BB * EE;
  const long n1 = n0 + (long)G4 * EE;
  const long n2 = n1 + (long)G4 * HH;
  long i = ((long)blockIdx.x * 256 + threadIdx.x) * 4;
  const float* src;
  ushort *dh, *dl;
  long off;
  if (i < n0) {
    src = x; dh = xh; dl = xl; off = i;
  } else if (i < n1) {
    src = Wih; dh = Wihh; dl = Wihl; off = i - n0;
  } else if (i < n2) {
    src = Whh; dh = Whhh; dl = Whhl; off = i - n1;
  } else {
    src = fcw; dh = fcwh; dl = fcwl; off = i - n2;
  }
  float4 v = *(const float4*)&src[off];
  ushort4 h;
  h.x = f2bf(v.x); h.y = f2bf(v.y); h.z = f2bf(v.z); h.w = f2bf(v.w);
  *(ushort4*)&dh[off] = h;
  ushort4 l;
  l.x = f2bf(v.x - bf2f(h.x));
  l.y = f2bf(v.y - bf2f(h.y));
  l.z = f2bf(v.z - bf2f(h.z));
  l.w = f2bf(v.w - bf2f(h.w));
  *(ushort4*)&dl[off] = l;
}

// ========== z = x @ W_ih^T + (b_ih+b_hh) -> zbuf fp32 [B][4H] ===========
__global__ void __launch_bounds__(256)
z_split(const ushort* __restrict__ xh, const ushort* __restrict__ xl,
        const ushort* __restrict__ Wihh, const ushort* __restrict__ Wihl,
        const float* __restrict__ bih, const float* __restrict__ bhh,
        float* __restrict__ zbuf) {
  __shared__ alignas(16) ushort Ah[64][72];
  __shared__ alignas(16) ushort Al[64][72];
  __shared__ alignas(16) ushort Bh[32][72];
  __shared__ alignas(16) ushort Bl[32][72];
  const int tid = threadIdx.x, bid = blockIdx.x;
  const int m0 = (bid >> 7) * 64;
  const int hbase = (bid & 127) * 8;
  const int lane = tid & 63, wave = tid >> 6;
  const int wm = wave & 1, wn = wave >> 1;
  const int fr_row = lane & 15, fr_k = (lane >> 4) * 8;
  const f32x4 fz = {0.f, 0.f, 0.f, 0.f};

  f32x4 a0 = fz, a1 = fz;
  for (int kt = 0; kt < EE / 64; ++kt) {
    for (int i = 0; i < 2; ++i) {
      int idx = tid + i * 256;
      int r = idx >> 3, c8 = (idx & 7) * 8;
      int go = (m0 + r) * EE + kt * 64 + c8;
      *(uint4*)&Ah[r][c8] = *(const uint4*)&xh[go];
      *(uint4*)&Al[r][c8] = *(const uint4*)&xl[go];
    }
    {
      int r = tid >> 3, c8 = (tid & 7) * 8;
      int wrow = (r >> 3) * HH + hbase + (r & 7);
      int go = wrow * EE + kt * 64 + c8;
      *(uint4*)&Bh[r][c8] = *(const uint4*)&Wihh[go];
      *(uint4*)&Bl[r][c8] = *(const uint4*)&Wihl[go];
    }
    __syncthreads();
    for (int kc = 0; kc < 2; ++kc) {
      int ko = kc * 32 + fr_k;
      s16x8 bh = *(const s16x8*)&Bh[wn * 16 + fr_row][ko];
      s16x8 bl = *(const s16x8*)&Bl[wn * 16 + fr_row][ko];
      s16x8 f0h = *(const s16x8*)&Ah[wm * 32 + fr_row][ko];
      s16x8 f0l = *(const s16x8*)&Al[wm * 32 + fr_row][ko];
      s16x8 f1h = *(const s16x8*)&Ah[wm * 32 + 16 + fr_row][ko];
      s16x8 f1l = *(const s16x8*)&Al[wm * 32 + 16 + fr_row][ko];
      a0 = mfma_bf16(f0h, bh, a0);
      a0 = mfma_bf16(f0l, bh, a0);
      a0 = mfma_bf16(f0h, bl, a0);
      a1 = mfma_bf16(f1h, bh, a1);
      a1 = mfma_bf16(f1l, bh, a1);
      a1 = mfma_bf16(f1h, bl, a1);
    }
    __syncthreads();
  }
  int jcol = wn * 16 + fr_row;
  int gc = (jcol >> 3) * HH + hbase + (jcol & 7);
  float bias = bih[gc] + bhh[gc];
  int rbase = wm * 32 + (lane >> 4) * 4;
#pragma unroll
  for (int r = 0; r < 4; ++r) {
    zbuf[(size_t)(m0 + rbase + r) * G4 + gc] = a0[r] + bias;
    zbuf[(size_t)(m0 + rbase + 16 + r) * G4 + gc] = a1[r] + bias;
  }
}

// =====================================================================
// Persistent kernel v7: touch-prefetch during the barrier wait.
//   v6 post-mortem: gates phase = L2-miss storm (per-step acquire-inv
//   empties L2; first toucher pays ~800cy L3 latency with ~3KB/CU in
//   flight) -> ~8us of the 14us step. v7 reorders the wait to
//   fence(inv) -> sync -> poll+TOUCH -> sync: as each block's flag
//   posts, a designated owner (one block per XCD per slice, via the
//   b>>3 intra-XCD index) pulls that 4KB slice into its XCD's L2 with
//   64 spaced plain loads. Post-inv touches are fresh-from-L3 and stay
//   valid for gates + next FC -> both run at L2-hit latency. Touches
//   kept live via asm sink; XCD mapping is perf-only (never wrong).
//   Everything else from v6: block-major h, sc1 full-line writes,
//   flag-array barrier, W_hh LDS-resident, FC in barrier slack.
// =====================================================================
__global__ void __launch_bounds__(NTHR, 2)
persist_kernel(const ushort* __restrict__ Whhh, const ushort* __restrict__ Whhl,
               const float* __restrict__ zbuf,
               ushort* __restrict__ hbh, ushort* __restrict__ hbl,
               const ushort* __restrict__ fcwh, const ushort* __restrict__ fcwl,
               const float* __restrict__ fcb, float* __restrict__ out,
               float* __restrict__ out_ns, unsigned* __restrict__ flags,
               int T) {
  extern __shared__ char smem[];
  char* WlB = smem + 65536;               // lo plane
  float* red = (float*)(smem + 131072);   // [128][RED36] f32 (also FC 8x256)

  const int tid = threadIdx.x;
  const int hb = blockIdx.x;      // h-slice (8 cols) = k-block it produces
  const int lane = tid & 63;
  const int w = tid >> 6;         // 0..7 (= gates m-tile)
  const int fr = lane & 15;
  const int fk8 = (lane >> 4) * 8;
  const int swz = (fr & 7) << 4;
  const f32x4 fz = {0.f, 0.f, 0.f, 0.f};

  // ---- stage W_hh tile into LDS once (swizzled) ----
  for (int i = tid; i < 32 * 128; i += NTHR) {
    int r = i >> 7;                 // local gate row (= g*8+c)
    int cb = (i & 127) * 16;        // byte within row
    int g = r >> 3, c = r & 7;
    size_t go = ((size_t)(g * HH + hb * 8 + c)) * (HH * 2) + (size_t)cb;
    int lofs = r * 2048 + (cb ^ ((r & 7) << 4));
    *(uint4*)(smem + lofs) = *(const uint4*)((const char*)Whhh + go);
    *(uint4*)(WlB + lofs) = *(const uint4*)((const char*)Whhl + go);
  }

  // ---- per-thread cell state + z preload (2 cells/thread) ----
  const int crow = tid >> 3, ccol = tid & 7;  // rows crow and crow+64
  float creg0 = 0.f, creg1 = 0.f;
  size_t zb0 = (size_t)crow * G4 + hb * 8 + ccol;
  size_t zb1 = (size_t)(crow + 64) * G4 + hb * 8 + ccol;
  float zi0 = zbuf[zb0], zf0 = zbuf[zb0 + HH];
  float zg0 = zbuf[zb0 + 2 * HH], zo0 = zbuf[zb0 + 3 * HH];
  float zi1 = zbuf[zb1], zf1 = zbuf[zb1 + HH];
  float zg1 = zbuf[zb1 + 2 * HH], zo1 = zbuf[zb1 + 3 * HH];

  // ---- FC constants: block = 16 out-rows x 32 out-cols; 8 waves =
  //      2 col-halves x 4-way K-split(256). frags in regs (static idx).
  const int m0f = (hb >> 4) * 16;
  const int o0 = (hb & 15) * 32;
  const int wo = w & 1, wkf = w >> 1;
  s16x8 fbh[8], fbl[8];
  {
    size_t base = (size_t)(o0 + wo * 16 + fr) * HH + wkf * 256 + fk8;
#pragma unroll
    for (int j = 0; j < 8; ++j) {
      fbh[j] = *(const s16x8*)&fcwh[base + j * 32];
      fbl[j] = *(const s16x8*)&fcwl[base + j * 32];
    }
  }
  const float fcbv = fcb[o0 + (tid >> 8) * 16 + (tid & 15)];
  __syncthreads();  // W staged

  for (int t = 0; t <= T; ++t) {
    if (t < T) {
      if (t > 0) {
        // ---- gates: h_{t-1} @ Whh^T, full K per wave; 3-deep
        //      4-kb-chunk register prefetch. Block-major layout:
        //      lane base = row*8 + q*1024, chunk offset (c*16+j*4)*1024
        const ushort* hph = hbh + (size_t)((t - 1) & 3) * (BB * HH);
        const ushort* hpl = hbl + (size_t)((t - 1) & 3) * (BB * HH);
        const ushort* ha =
            hph + (size_t)(w * 16 + fr) * 8 + (size_t)(lane >> 4) * (BB * 8);
        const ushort* la =
            hpl + (size_t)(w * 16 + fr) * 8 + (size_t)(lane >> 4) * (BB * 8);
        f32x4 a0 = fz, a1 = fz;
        s16x8 ph[3][4], pl[3][4];
#pragma unroll
        for (int j = 0; j < 4; ++j) {
          ph[0][j] = *(const s16x8*)&ha[(j * 4) * (BB * 8)];
          pl[0][j] = *(const s16x8*)&la[(j * 4) * (BB * 8)];
        }
#pragma unroll
        for (int j = 0; j < 4; ++j) {
          ph[1][j] = *(const s16x8*)&ha[(16 + j * 4) * (BB * 8)];
          pl[1][j] = *(const s16x8*)&la[(16 + j * 4) * (BB * 8)];
        }
#pragma unroll
        for (int c = 0; c < 8; ++c) {
          if (c + 2 < 8) {
#pragma unroll
            for (int j = 0; j < 4; ++j) {
              ph[(c + 2) % 3][j] =
                  *(const s16x8*)&ha[((c + 2) * 16 + j * 4) * (BB * 8)];
              pl[(c + 2) % 3][j] =
                  *(const s16x8*)&la[((c + 2) * 16 + j * 4) * (BB * 8)];
            }
          }
#pragma unroll
          for (int j = 0; j < 4; ++j) {
            int kk = c * 128 + j * 32 + fk8;
            int sw = (kk * 2) ^ swz;
            int ofs0 = fr * 2048 + sw;
            int ofs1 = (16 + fr) * 2048 + sw;
            s16x8 bh0 = *(const s16x8*)(smem + ofs0);
            s16x8 bl0 = *(const s16x8*)(WlB + ofs0);
            s16x8 bh1 = *(const s16x8*)(smem + ofs1);
            s16x8 bl1 = *(const s16x8*)(WlB + ofs1);
            a0 = mfma_bf16(ph[c % 3][j], bh0, a0);
            a0 = mfma_bf16(pl[c % 3][j], bh0, a0);
            a0 = mfma_bf16(ph[c % 3][j], bl0, a0);
            a1 = mfma_bf16(ph[c % 3][j], bh1, a1);
            a1 = mfma_bf16(pl[c % 3][j], bh1, a1);
            a1 = mfma_bf16(ph[c % 3][j], bl1, a1);
          }
        }
        // ---- scatter complete gate sums ----
        int rrow = w * 16 + (lane >> 4) * 4;
#pragma unroll
        for (int r = 0; r < 4; ++r) {
          red[(rrow + r) * RED36 + fr] = a0[r];
          red[(rrow + r) * RED36 + 16 + fr] = a1[r];
        }
        __syncthreads();
      }
      // ---- LSTM cell (fp32, c in regs); h_t stored block-major:
      //      offsets tid and 512+tid -> wave-contiguous full lines ----
      {
        float gi0 = zi0, gf0 = zf0, gg0 = zg0, go0 = zo0;
        float gi1 = zi1, gf1 = zf1, gg1 = zg1, go1 = zo1;
        if (t > 0) {
          const float* r0 = red + crow * RED36;
          const float* r1 = red + (crow + 64) * RED36;
          gi0 += r0[ccol];      gi1 += r1[ccol];
          gf0 += r0[8 + ccol];  gf1 += r1[8 + ccol];
          gg0 += r0[16 + ccol]; gg1 += r1[16 + ccol];
          go0 += r0[24 + ccol]; go1 += r1[24 + ccol];
        }
        float iv0 = sigm(gi0), fv0 = sigm(gf0), gv0 = tanhf(gg0), ov0 = sigm(go0);
        float iv1 = sigm(gi1), fv1 = sigm(gf1), gv1 = tanhf(gg1), ov1 = sigm(go1);
        creg0 = fv0 * creg0 + iv0 * gv0;
        creg1 = fv1 * creg1 + iv1 * gv1;
        float hv0 = ov0 * tanhf(creg0);
        float hv1 = ov1 * tanhf(creg1);
        ushort hh0 = f2bf(hv0), hl0 = f2bf(hv0 - bf2f(hh0));
        ushort hh1 = f2bf(hv1), hl1 = f2bf(hv1 - bf2f(hh1));
        size_t hob = (size_t)(t & 3) * (BB * HH) + (size_t)hb * (BB * 8);
        store_short_agent(hbh + hob + tid, hh0);         // row crow
        store_short_agent(hbl + hob + tid, hl0);
        store_short_agent(hbh + hob + 512 + tid, hh1);   // row crow+64
        store_short_agent(hbl + hob + 512 + tid, hl1);
        if (t == T - 1 && crow == 63) out_ns[hb * 8 + ccol] = hv1;
      }
      // ---- barrier arrive: syncthreads' vmcnt(0) drains the sc1
      //      stores (full-line write-through, globally visible); flag.
      __syncthreads();
      if (tid == 0) {
        __hip_atomic_store(&flags[hb * FLAGSTRIDE], (unsigned)(t + 1),
                           __ATOMIC_RELAXED, __HIP_MEMORY_SCOPE_AGENT);
      }
    }
    // ---- delayed FC for h_{t-1}: overlapped with barrier slack
    //      (reads lines warmed by last step's touch phase) ----
    if (t > 0) {
      const ushort* hch = hbh + (size_t)((t - 1) & 3) * (BB * HH);
      const ushort* hcl = hbl + (size_t)((t - 1) & 3) * (BB * HH);
      const ushort* hca =
          hch + (size_t)(m0f + fr) * 8 + (size_t)(lane >> 4) * (BB * 8);
      const ushort* hcb =
          hcl + (size_t)(m0f + fr) * 8 + (size_t)(lane >> 4) * (BB * 8);
      f32x4 acc = fz;
#pragma unroll
      for (int j = 0; j < 8; ++j) {
        s16x8 afh = *(const s16x8*)&hca[(wkf * 32 + j * 4) * (BB * 8)];
        s16x8 afl = *(const s16x8*)&hcb[(wkf * 32 + j * 4) * (BB * 8)];
        acc = mfma_bf16(afh, fbh[j], acc);
        acc = mfma_bf16(afl, fbh[j], acc);
        acc = mfma_bf16(afh, fbl[j], acc);
      }
      int rb = (lane >> 4) * 4;
      float* rp = red + (wkf * 2 + wo) * 256;
#pragma unroll
      for (int r = 0; r < 4; ++r) rp[(rb + r) * 16 + fr] = acc[r];
      __syncthreads();
      {
        int wo2 = tid >> 8, row = (tid >> 4) & 15, col = tid & 15;
        float s = fcbv;
#pragma unroll
        for (int k = 0; k < 4; ++k)
          s += red[(k * 2 + wo2) * 256 + row * 16 + col];
        out[((size_t)(m0f + row) * T + (t - 1)) * OO + o0 + wo2 * 16 + col] = s;
      }
    }
    // ---- barrier wait v7: inv FIRST, then poll + touch-prefetch.
    //      Post-inv touches pull fresh L3 lines into this XCD's L2 and
    //      survive into the gates phase (next inv is a full step away).
    if (t < T) {
      if (tid < 64) __builtin_amdgcn_fence(__ATOMIC_ACQUIRE, "agent");
      __syncthreads();  // inv complete before touches
      if (tid < NBLKP) {
        const int i = tid;  // poller i watches block i's flag
        unsigned tgt = (unsigned)(t + 1);
        unsigned spins = 0;
        while (__hip_atomic_load(&flags[i * FLAGSTRIDE], __ATOMIC_RELAXED,
                                 __HIP_MEMORY_SCOPE_AGENT) < tgt) {
          __builtin_amdgcn_s_sleep(1);
          if (++spins > SPIN_LIMIT) break;  // hang-proof bail
        }
        // owner: one block per XCD per slice (intra-XCD index b>>3);
        // touch slice i (4KB hi+lo) at 64B stride -> fills L2 lines
        if ((i >> 3) == (hb >> 3)) {
          const uint* ph =
              (const uint*)(hbh + (size_t)(t & 3) * (BB * HH) + i * (BB * 8));
          const uint* pl =
              (const uint*)(hbl + (size_t)(t & 3) * (BB * HH) + i * (BB * 8));
          unsigned acc = 0;
#pragma unroll
          for (int k2 = 0; k2 < 32; ++k2) {
            acc += ph[k2 * 16];   // one dword per 64B
            acc += pl[k2 * 16];
          }
          asm volatile("" :: "v"(acc));  // keep touches live (no DCE)
        }
      }
      __syncthreads();
    }
  }
}

extern "C" void kernel_launch(void* const* d_in, const int* in_sizes, int n_in,
                              void* d_out, int out_size, void* d_ws,
                              size_t ws_size, hipStream_t stream) {
  (void)ws_size;
  // ---- order-agnostic input identification by element count ----
  const float *x = nullptr, *Wih = nullptr, *Whh = nullptr, *fcw = nullptr;
  const float *bih = nullptr, *bhh = nullptr, *fcb = nullptr;
  for (int i = 0; i < n_in; ++i) {
    int s = in_sizes[i];
    const float* p = (const float*)d_in[i];
    if (s == BB * EE && !x) x = p;
    else if (s == G4 * EE && !Wih) Wih = p;
    else if (s == G4 * HH && !Whh) Whh = p;
    else if (s == OO * HH && !fcw) fcw = p;
    else if (s == G4 && !bih) bih = p;
    else if (s == G4 && !bhh) bhh = p;  // bias order irrelevant (summed)
    else if (s == OO && !fcb) fcb = p;
  }
  if (!x || !Wih || !Whh || !fcw || !bih || !bhh || !fcb) return;

  // ---- runtime T from out_size ----
  int T = 0;
  if (out_size >= BB * OO && (out_size - HH) % (BB * OO) == 0 &&
      (out_size - HH) / (BB * OO) >= 1) {
    T = (out_size - HH) / (BB * OO);
  } else if (out_size % (BB * OO) == 0) {
    T = out_size / (BB * OO);
  }
  if (T < 1 || T > 16384) return;

  float* out = (float*)d_out;
  float* out_ns = out + (size_t)BB * T * OO;

  // ---- ws layout ----
  ushort* xh = (ushort*)d_ws;
  ushort* xl = xh + (size_t)BB * EE;
  ushort* Wihh = xl + (size_t)BB * EE;
  ushort* Wihl = Wihh + (size_t)G4 * EE;
  ushort* Whhh = Wihl + (size_t)G4 * EE;
  ushort* Whhl = Whhh + (size_t)G4 * HH;
  ushort* fcwh = Whhl + (size_t)G4 * HH;
  ushort* fcwl = fcwh + (size_t)OO * HH;
  ushort* hbh = fcwl + (size_t)OO * HH;               // 4 x B x H (4-deep)
  ushort* hbl = hbh + (size_t)4 * BB * HH;
  float* zbuf = (float*)(hbl + (size_t)4 * BB * HH);  // 128*4096 f32
  unsigned* flags = (unsigned*)(zbuf + (size_t)BB * G4);  // 128 x 16 uints

  {
    long total = (long)BB * EE + (long)G4 * EE + (long)G4 * HH + (long)OO * HH;
    int cblocks = (int)(total / 4 / 256);  // exact
    hipLaunchKernelGGL(convert_split, dim3(cblocks), dim3(256), 0, stream, x,
                       Wih, Whh, fcw, xh, xl, Wihh, Wihl, Whhh, Whhl, fcwh,
                       fcwl, flags);
  }
  hipLaunchKernelGGL(z_split, dim3(256), dim3(256), 0, stream, xh, xl, Wihh,
                     Wihl, bih, bhh, zbuf);

  static int attr_set = 0;
  if (!attr_set) {
    (void)hipFuncSetAttribute((const void*)persist_kernel,
                              hipFuncAttributeMaxDynamicSharedMemorySize,
                              SMEM_BYTES);
    attr_set = 1;
  }
  // PLAIN launch (graph-capture-safe). 128 blocks, 1 block/CU on 256 CUs
  // -> co-residency with 2x headroom; spin bail guards the residual risk.
  hipLaunchKernelGGL(persist_kernel, dim3(NBLKP), dim3(NTHR), SMEM_BYTES,
                     stream, Whhh, Whhl, zbuf, hbh, hbl, fcwh, fcwl, fcb, out,
                     out_ns, flags, T);
}